// Round 14
// baseline (452.832 us; speedup 1.0000x reference)
//
#include <hip/hip_runtime.h>
#include <hip/hip_bf16.h>
#include <float.h>
#include <math.h>

// Problem constants (from reference)
#define NN 20000
#define EE 320000
#define IN_DIM 128
#define SLOPE_ 0.2f

typedef __attribute__((ext_vector_type(8))) short bf16x8;
typedef __attribute__((ext_vector_type(4))) float f32x4;
typedef _Float16 f16;
typedef __attribute__((ext_vector_type(2))) _Float16 f16x2;
typedef __attribute__((ext_vector_type(8))) _Float16 f16x8;
typedef unsigned short ushort;
typedef __attribute__((ext_vector_type(8))) unsigned short ushort8;

// ---------- bf16 helpers ----------
__device__ inline ushort f32_to_bf16_rn(float f) {
    unsigned u = __float_as_uint(f);
    unsigned rounding = 0x7FFFu + ((u >> 16) & 1u);
    return (ushort)((u + rounding) >> 16);
}
__device__ inline float bf16u_to_f32(ushort h) {
    return __uint_as_float(((unsigned)h) << 16);
}

// ---------- weight prep element: concat + transpose + split ----------
__device__ inline void prep_elem(const float* __restrict__ Wa, const float* __restrict__ ba, int na,
                                 const float* __restrict__ Wb, const float* __restrict__ bb, int nb,
                                 const float* __restrict__ Wc, const float* __restrict__ bc, int nc,
                                 int K, ushort* __restrict__ Wth, ushort* __restrict__ Wtl,
                                 float* __restrict__ bias_cat, int idx) {
    int n = idx / K;
    int k = idx - n * K;
    const float* W; const float* b; int nl; int ncols;
    if (n < na) { W = Wa; b = ba; nl = n; ncols = na; }
    else if (n < na + nb) { W = Wb; b = bb; nl = n - na; ncols = nb; }
    else { W = Wc; b = bc; nl = n - na - nb; ncols = nc; }
    float v = W[(size_t)k * ncols + nl];
    ushort h = f32_to_bf16_rn(v);
    ushort l = f32_to_bf16_rn(v - bf16u_to_f32(h));
    Wth[(size_t)n * K + k] = h;
    Wtl[(size_t)n * K + k] = l;
    if (k == 0) bias_cat[n] = b[nl];
}

// ---------- one launch: all 3 weight preps + x split ----------
#define SEG0 (512 * 128)
#define SEG1 (512 * 256)
#define SEG2 (576 * 256)
#define SEG3 (NN * IN_DIM / 4)
__global__ void prep_all(const float* __restrict__ W0s, const float* __restrict__ b0s,
                         const float* __restrict__ W0d, const float* __restrict__ b0d,
                         const float* __restrict__ W1s, const float* __restrict__ b1s,
                         const float* __restrict__ W1d, const float* __restrict__ b1d,
                         const float* __restrict__ W2s, const float* __restrict__ b2s,
                         const float* __restrict__ W2d, const float* __restrict__ b2d,
                         const float* __restrict__ Wr2, const float* __restrict__ br2,
                         const float* __restrict__ x,
                         ushort* __restrict__ Wt0h, ushort* __restrict__ Wt0l, float* __restrict__ bias0,
                         ushort* __restrict__ Wt1h, ushort* __restrict__ Wt1l, float* __restrict__ bias1,
                         ushort* __restrict__ Wt2h, ushort* __restrict__ Wt2l, float* __restrict__ bias2,
                         ushort* __restrict__ Ah, ushort* __restrict__ Al) {
    int idx = blockIdx.x * 256 + threadIdx.x;
    if (idx < SEG0) {
        prep_elem(W0s, b0s, 256, W0d, b0d, 256, nullptr, nullptr, 0, 128, Wt0h, Wt0l, bias0, idx);
    } else if ((idx -= SEG0) < SEG1) {
        prep_elem(W1s, b1s, 256, W1d, b1d, 256, nullptr, nullptr, 0, 256, Wt1h, Wt1l, bias1, idx);
    } else if ((idx -= SEG1) < SEG2) {
        prep_elem(W2s, b2s, 192, W2d, b2d, 192, Wr2, br2, 192, 256, Wt2h, Wt2l, bias2, idx);
    } else if ((idx -= SEG2) < SEG3) {
        float4 v = ((const float4*)x)[idx];
        ushort h0 = f32_to_bf16_rn(v.x), h1 = f32_to_bf16_rn(v.y);
        ushort h2 = f32_to_bf16_rn(v.z), h3 = f32_to_bf16_rn(v.w);
        ushort l0 = f32_to_bf16_rn(v.x - bf16u_to_f32(h0));
        ushort l1 = f32_to_bf16_rn(v.y - bf16u_to_f32(h1));
        ushort l2 = f32_to_bf16_rn(v.z - bf16u_to_f32(h2));
        ushort l3 = f32_to_bf16_rn(v.w - bf16u_to_f32(h3));
        ((ushort4*)Ah)[idx] = make_ushort4(h0, h1, h2, h3);
        ((ushort4*)Al)[idx] = make_ushort4(l0, l1, l2, l3);
    }
}

// ---------- split-bf16 MFMA GEMM: NO LDS, direct global->VGPR B fragments ----------
// BM=128 (4 waves x 32 rows, mt=2), BN=64, BK=32. No barriers at all — the B-fragment
// MFMA layout (n=nt*16+m16 row, k=quad*8 contiguous) is the same contiguous-16B shape
// as A, so waves load B straight from Wt; 4 waves/block hit the same lines in L1.
// Cols [0,b1)->F0(f16), [b1,b2)->F1(f16), [b2,S)->F2(f32).
__global__ __launch_bounds__(256) void gemm_mfma_split(
        const ushort* __restrict__ Ahi, const ushort* __restrict__ Alo,
        const ushort* __restrict__ Wth, const ushort* __restrict__ Wtl,
        const float* __restrict__ bias,
        f16* __restrict__ F0, f16* __restrict__ F1, float* __restrict__ F2,
        int b1, int b2, int M, int K, int S, int gx, int gy) {
    const int bid = blockIdx.x;
    const int p = bid & 7;          // XCD slot
    const int q = bid >> 3;
    const int bn_i = q % gx;
    const int bm_i = (q / gx) * 8 + p;
    if (bm_i >= gy) return;
    const int bm = bm_i * 128;
    const int bn = bn_i * 64;

    const int tid = threadIdx.x;
    const int wave = tid >> 6;
    const int lane = tid & 63;
    const int m16 = lane & 15;
    const int quad = lane >> 4;

    f32x4 acc[2][4];
    #pragma unroll
    for (int i = 0; i < 2; ++i)
        #pragma unroll
        for (int j = 0; j < 4; ++j) acc[i][j] = (f32x4){0.f, 0.f, 0.f, 0.f};

    // fragment base offsets (elements); add k0 each step
    size_t aoff[2], boff[4];
    #pragma unroll
    for (int mt = 0; mt < 2; ++mt) {
        int row = bm + wave * 32 + mt * 16 + m16;
        row = row < M ? row : M - 1;
        aoff[mt] = (size_t)row * K + quad * 8;
    }
    #pragma unroll
    for (int nt = 0; nt < 4; ++nt)
        boff[nt] = (size_t)(bn + nt * 16 + m16) * K + quad * 8;

    #pragma unroll 2
    for (int k0 = 0; k0 < K; k0 += 32) {
        bf16x8 ah[2], al[2], bh[4], bl[4];
        #pragma unroll
        for (int mt = 0; mt < 2; ++mt) {
            ah[mt] = *(const bf16x8*)(Ahi + aoff[mt] + k0);
            al[mt] = *(const bf16x8*)(Alo + aoff[mt] + k0);
        }
        #pragma unroll
        for (int nt = 0; nt < 4; ++nt) {
            bh[nt] = *(const bf16x8*)(Wth + boff[nt] + k0);
            bl[nt] = *(const bf16x8*)(Wtl + boff[nt] + k0);
        }
        #pragma unroll
        for (int nt = 0; nt < 4; ++nt) {
            #pragma unroll
            for (int mt = 0; mt < 2; ++mt) {
                acc[mt][nt] = __builtin_amdgcn_mfma_f32_16x16x32_bf16(ah[mt], bh[nt], acc[mt][nt], 0, 0, 0);
                acc[mt][nt] = __builtin_amdgcn_mfma_f32_16x16x32_bf16(ah[mt], bl[nt], acc[mt][nt], 0, 0, 0);
                acc[mt][nt] = __builtin_amdgcn_mfma_f32_16x16x32_bf16(al[mt], bh[nt], acc[mt][nt], 0, 0, 0);
            }
        }
    }

    // epilogue: route 16-col tiles (boundaries are x64, so no tile straddles)
    #pragma unroll
    for (int nt = 0; nt < 4; ++nt) {
        int col0 = bn + nt * 16;
        float bv = bias[col0 + m16];
        if (col0 < b1) {
            int col = col0 + m16;
            #pragma unroll
            for (int mt = 0; mt < 2; ++mt)
                #pragma unroll
                for (int r = 0; r < 4; ++r) {
                    int row = bm + wave * 32 + mt * 16 + quad * 4 + r;
                    if (row < M) F0[(size_t)row * b1 + col] = (f16)(acc[mt][nt][r] + bv);
                }
        } else if (col0 < b2) {
            int col = col0 - b1 + m16;
            int cs = b2 - b1;
            #pragma unroll
            for (int mt = 0; mt < 2; ++mt)
                #pragma unroll
                for (int r = 0; r < 4; ++r) {
                    int row = bm + wave * 32 + mt * 16 + quad * 4 + r;
                    if (row < M) F1[(size_t)row * cs + col] = (f16)(acc[mt][nt][r] + bv);
                }
        } else {
            int col = col0 - b2 + m16;
            int cs = S - b2;
            #pragma unroll
            for (int mt = 0; mt < 2; ++mt)
                #pragma unroll
                for (int r = 0; r < 4; ++r) {
                    int row = bm + wave * 32 + mt * 16 + quad * 4 + r;
                    if (row < M) F2[(size_t)row * cs + col] = acc[mt][nt][r] + bv;
                }
        }
    }
}

// ---------- CSR build ----------
__global__ void zero_u32(unsigned int* __restrict__ p, int n) {
    int i = blockIdx.x * blockDim.x + threadIdx.x;
    if (i < n) p[i] = 0u;
}

__global__ void hist_dst(const int* __restrict__ dst, unsigned int* __restrict__ deg, int E) {
    int e = blockIdx.x * blockDim.x + threadIdx.x;
    if (e < E) atomicAdd(&deg[dst[e]], 1u);
}

__global__ void scan_deg(const unsigned int* __restrict__ deg,
                         unsigned int* __restrict__ row_ptr,
                         unsigned int* __restrict__ cursor, int n) {
    __shared__ unsigned int sums[1024];
    const int t = threadIdx.x;
    const int chunk = (n + 1023) / 1024;
    const int start = t * chunk;
    const int end = min(start + chunk, n);
    unsigned int s = 0;
    for (int i = start; i < end; ++i) s += deg[i];
    sums[t] = s;
    __syncthreads();
    for (int off = 1; off < 1024; off <<= 1) {
        unsigned int v = (t >= off) ? sums[t - off] : 0u;
        __syncthreads();
        sums[t] += v;
        __syncthreads();
    }
    unsigned int prefix = (t == 0) ? 0u : sums[t - 1];
    for (int i = start; i < end; ++i) {
        row_ptr[i] = prefix;
        cursor[i] = prefix;
        prefix += deg[i];
    }
    if (t == 1023) row_ptr[n] = sums[1023];
}

__global__ void scatter_edges(const int* __restrict__ src, const int* __restrict__ dst,
                              unsigned int* __restrict__ cursor,
                              int* __restrict__ csr_src, int E) {
    int e = blockIdx.x * blockDim.x + threadIdx.x;
    if (e < E) {
        unsigned int pos = atomicAdd(&cursor[dst[e]], 1u);
        csr_src[pos] = src[e];
    }
}

// ---------- fused GATv2 aggregate: 2 nodes per wave, 8 f16 dims per lane ----------
// Logit dot in packed f16 (v_pk_add_f16 + |x| via and-mask + v_dot2_f32_f16).
// Plain exp-sum (logits bounded). Scalar per-position clamped index prefetch.
// OUT_MODE: 0 = fp32 out + bf16 hi/lo; 1 = bf16 hi/lo only; 2 = head-mean -> out[N,32].
template <int HD, int D, bool HAS_RES, bool DO_ELU, int OUT_MODE>
__global__ __launch_bounds__(256) void gat_node_aggregate(
        const f16* __restrict__ fsb, const f16* __restrict__ fdb,
        const float* __restrict__ attn,
        const unsigned int* __restrict__ row_ptr,
        const int* __restrict__ csr_src,
        const float* __restrict__ resid, int RS,
        float* __restrict__ outF, ushort* __restrict__ outH, ushort* __restrict__ outL) {
    constexpr int LANES = HD / 8;   // active lanes per node (32 or 24)
    constexpr int GSZ = D / 8;      // lanes per head group (8 or 4)
    __shared__ float red[(OUT_MODE == 2) ? 8 : 1][(OUT_MODE == 2) ? HD : 1];

    const int wave = threadIdx.x >> 6;
    const int lane = threadIdx.x & 63;
    const int half = lane >> 5;            // 0 = node A, 1 = node B
    const int ln = lane & 31;              // lane within node
    const int t = blockIdx.x * 8 + wave * 2 + half;
    const bool active = (ln < LANES);
    const unsigned off = active ? 8u * ln : 0u;   // inactive lanes alias dims 0-7

    f16x2 fdp[4], a6p[4], a4p[4];
    if (active) {
        f16x8 dv = *(const f16x8*)&fdb[(unsigned)t * HD + off];
        float4 aA = *(const float4*)&attn[off];
        float4 aB = *(const float4*)&attn[off + 4];
        float av[8] = {aA.x, aA.y, aA.z, aA.w, aB.x, aB.y, aB.z, aB.w};
        #pragma unroll
        for (int i = 0; i < 4; ++i) {
            fdp[i] = (f16x2){dv[2 * i], dv[2 * i + 1]};
            a6p[i] = (f16x2){(f16)(0.6f * av[2 * i]), (f16)(0.6f * av[2 * i + 1])};
            a4p[i] = (f16x2){(f16)(0.4f * av[2 * i]), (f16)(0.4f * av[2 * i + 1])};
        }
    } else {
        #pragma unroll
        for (int i = 0; i < 4; ++i) {
            fdp[i] = (f16x2){0, 0};
            a6p[i] = (f16x2){0, 0};
            a4p[i] = (f16x2){0, 0};
        }
    }

    const int jj0 = (int)row_ptr[t];
    const int jj1 = (int)row_ptr[t + 1];
    const int deg = jj1 - jj0;
    const int last = jj1 - 1;
    const int degO = __shfl_xor(deg, 32, 64);
    const int mdeg = max(deg, degO);       // wave-uniform loop bound

    float acc[8];
    #pragma unroll
    for (int d = 0; d < 8; ++d) acc[d] = 0.f;
    float lh = 0.f;

    // prologue: features for edges 0..7, indices for refill edges 8..15 (all clamped)
    f16x8 buf[8];
    int cidx[8];
    #pragma unroll
    for (int u = 0; u < 8; ++u) {
        int e0 = min(jj0 + u, last);
        buf[u] = *(const f16x8*)&fsb[(unsigned)csr_src[e0] * HD + off];
        cidx[u] = csr_src[min(jj0 + 8 + u, last)];
    }

    for (int b = 0; b < mdeg; b += 8) {
        // indices for NEXT batch's refills (edges b+16..b+23), clamped per position
        int nidx[8];
        #pragma unroll
        for (int u = 0; u < 8; ++u)
            nidx[u] = csr_src[min(jj0 + b + 16 + u, last)];
        #pragma unroll
        for (int u = 0; u < 8; ++u) {
            const f16x8 cur = buf[u];
            buf[u] = *(const f16x8*)&fsb[(unsigned)cidx[u] * HD + off];  // edge b+8+u
            // packed-f16 logit dot: p = sum x*(0.6a) + |x|*(0.4a), f32 accumulate
            float p = 0.f;
            #pragma unroll
            for (int i = 0; i < 4; ++i) {
                f16x2 cp = (f16x2){cur[2 * i], cur[2 * i + 1]};
                f16x2 xp = cp + fdp[i];                       // v_pk_add_f16
                unsigned xu = __builtin_bit_cast(unsigned, xp) & 0x7FFF7FFFu;
                f16x2 xa = __builtin_bit_cast(f16x2, xu);     // packed |x|
                p = __builtin_amdgcn_fdot2(xp, a6p[i], p, false);
                p = __builtin_amdgcn_fdot2(xa, a4p[i], p, false);
            }
            #pragma unroll
            for (int o = 1; o < GSZ; o <<= 1)
                p += __shfl_xor(p, o, 64);
            float w = (b + u < deg) ? __expf(p) : 0.f;
            lh += w;
            #pragma unroll
            for (int d = 0; d < 8; ++d) acc[d] += w * (float)cur[d];   // fma_mix
        }
        #pragma unroll
        for (int u = 0; u < 8; ++u) cidx[u] = nidx[u];
    }

    float inv = (lh > 0.f) ? 1.f / lh : 0.f;
    float vout[8];
    #pragma unroll
    for (int d = 0; d < 8; ++d) vout[d] = acc[d] * inv;
    if (HAS_RES && active) {
        float4 rA = *(const float4*)&resid[(unsigned)t * RS + off];
        float4 rB = *(const float4*)&resid[(unsigned)t * RS + off + 4];
        vout[0] += rA.x; vout[1] += rA.y; vout[2] += rA.z; vout[3] += rA.w;
        vout[4] += rB.x; vout[5] += rB.y; vout[6] += rB.z; vout[7] += rB.w;
    }
    if (DO_ELU) {
        #pragma unroll
        for (int d = 0; d < 8; ++d) vout[d] = vout[d] > 0.f ? vout[d] : expm1f(vout[d]);
    }

    if (OUT_MODE == 2) {
        const int nib = wave * 2 + half;
        if (active) {
            *(float4*)&red[nib][off] = make_float4(vout[0], vout[1], vout[2], vout[3]);
            *(float4*)&red[nib][off + 4] = make_float4(vout[4], vout[5], vout[6], vout[7]);
        }
        __syncthreads();
        // 8 nodes x 32 cols = 256 threads
        int node = threadIdx.x >> 5;
        int col = threadIdx.x & 31;
        float ssum = 0.f;
        #pragma unroll
        for (int h = 0; h < 6; ++h) ssum += red[node][h * 32 + col];
        outF[(unsigned)(blockIdx.x * 8 + node) * 32 + col] = ssum * (1.f / 6.f);
    } else if (active) {
        ushort8 hv, lv;
        #pragma unroll
        for (int d = 0; d < 8; ++d) {
            ushort h = f32_to_bf16_rn(vout[d]);
            hv[d] = h;
            lv[d] = f32_to_bf16_rn(vout[d] - bf16u_to_f32(h));
        }
        *(ushort8*)&outH[(unsigned)t * HD + off] = hv;
        *(ushort8*)&outL[(unsigned)t * HD + off] = lv;
        if (OUT_MODE == 0) {
            *(float4*)&outF[(unsigned)t * HD + off] = make_float4(vout[0], vout[1], vout[2], vout[3]);
            *(float4*)&outF[(unsigned)t * HD + off + 4] = make_float4(vout[4], vout[5], vout[6], vout[7]);
        }
    }
}

extern "C" void kernel_launch(void* const* d_in, const int* in_sizes, int n_in,
                              void* d_out, int out_size, void* d_ws, size_t ws_size,
                              hipStream_t stream) {
    const float* x   = (const float*)d_in[0];
    const int*   src = (const int*)d_in[1];
    const int*   dst = (const int*)d_in[2];
    const float* W0s = (const float*)d_in[3];
    const float* b0s = (const float*)d_in[4];
    const float* W0d = (const float*)d_in[5];
    const float* b0d = (const float*)d_in[6];
    const float* a0  = (const float*)d_in[7];
    const float* W1s = (const float*)d_in[8];
    const float* b1s = (const float*)d_in[9];
    const float* W1d = (const float*)d_in[10];
    const float* b1d = (const float*)d_in[11];
    const float* a1  = (const float*)d_in[12];
    const float* W2s = (const float*)d_in[13];
    const float* b2s = (const float*)d_in[14];
    const float* W2d = (const float*)d_in[15];
    const float* b2d = (const float*)d_in[16];
    const float* a2  = (const float*)d_in[17];
    const float* Wr2 = (const float*)d_in[18];
    const float* br2 = (const float*)d_in[19];

    // ---- workspace layout ----
    f16* FsH = (f16*)d_ws;                           // N*256 f16 (fs, dense gather target)
    f16* FdH = FsH + (size_t)NN * 256;               // N*256 f16 (fd)
    float* O0 = (float*)(FdH + (size_t)NN * 256);    // N*256 fp32 (L1 residual; later L2 Fr N*192)
    ushort* Ah = (ushort*)(O0 + (size_t)NN * 256);   // N*256 bf16
    ushort* Al = Ah + (size_t)NN * 256;              // N*256
    ushort* Wt0h = Al + (size_t)NN * 256;            // 512*128
    ushort* Wt0l = Wt0h + 512 * 128;
    ushort* Wt1h = Wt0l + 512 * 128;                 // 512*256
    ushort* Wt1l = Wt1h + 512 * 256;
    ushort* Wt2h = Wt1l + 512 * 256;                 // 576*256
    ushort* Wt2l = Wt2h + 576 * 256;
    float* bias0 = (float*)(Wt2l + 576 * 256);       // 512
    float* bias1 = bias0 + 512;                      // 512
    float* bias2 = bias1 + 512;                      // 576
    unsigned int* row_ptr = (unsigned int*)(bias2 + 576);  // N+1
    unsigned int* cursor  = row_ptr + (NN + 1);
    unsigned int* deg     = cursor + NN;
    int* csr_src          = (int*)(deg + NN);        // E

    // ---- build CSR ----
    zero_u32<<<(NN + 255) / 256, 256, 0, stream>>>(deg, NN);
    hist_dst<<<(EE + 255) / 256, 256, 0, stream>>>(dst, deg, EE);
    scan_deg<<<1, 1024, 0, stream>>>(deg, row_ptr, cursor, NN);
    scatter_edges<<<(EE + 255) / 256, 256, 0, stream>>>(src, dst, cursor, csr_src, EE);

    // ---- all weight prep + x split in ONE launch ----
    {
        int total = SEG0 + SEG1 + SEG2 + SEG3;
        prep_all<<<(total + 255) / 256, 256, 0, stream>>>(
            W0s, b0s, W0d, b0d, W1s, b1s, W1d, b1d, W2s, b2s, W2d, b2d, Wr2, br2, x,
            Wt0h, Wt0l, bias0, Wt1h, Wt1l, bias1, Wt2h, Wt2l, bias2, Ah, Al);
    }

    const int gy = (NN + 127) / 128;           // 157 bm tiles
    const int gy8 = ((gy + 7) / 8) * 8;        // 160 (rounded for swizzle)
    const int nagg = NN / 8;                   // 2500 blocks, 8 nodes each (2 per wave)

    // ---- layer 0: x[N,128] -> FsH/FdH[N,256] f16 -> O0 fp32 + Ah/Al bf16 ----
    gemm_mfma_split<<<gy8 * 8, 256, 0, stream>>>(Ah, Al, Wt0h, Wt0l, bias0,
                                                 FsH, FdH, nullptr, 256, 512, NN, 128, 512, 8, gy);
    gat_node_aggregate<256, 64, false, true, 0><<<nagg, 256, 0, stream>>>(
        FsH, FdH, a0, row_ptr, csr_src, nullptr, 0, O0, Ah, Al);

    // ---- layer 1: Ah/Al -> FsH/FdH[N,256] -> Ah/Al (identity residual O0 fp32) ----
    gemm_mfma_split<<<gy8 * 8, 256, 0, stream>>>(Ah, Al, Wt1h, Wt1l, bias1,
                                                 FsH, FdH, nullptr, 256, 512, NN, 256, 512, 8, gy);
    gat_node_aggregate<256, 64, true, true, 1><<<nagg, 256, 0, stream>>>(
        FsH, FdH, a1, row_ptr, csr_src, O0, 256, nullptr, Ah, Al);

    // ---- layer 2: Ah/Al -> FsH/FdH[N,192] + Fr(=O0 fp32)[N,192] -> d_out[N,32] ----
    gemm_mfma_split<<<gy8 * 9, 256, 0, stream>>>(Ah, Al, Wt2h, Wt2l, bias2,
                                                 FsH, FdH, O0, 192, 384, NN, 256, 576, 9, gy);
    gat_node_aggregate<192, 32, true, false, 2><<<nagg, 256, 0, stream>>>(
        FsH, FdH, a2, row_ptr, csr_src, O0, 192, (float*)d_out, nullptr, nullptr);
}

// Round 15
// 366.443 us; speedup vs baseline: 1.2358x; 1.2358x over previous
//
#include <hip/hip_runtime.h>
#include <hip/hip_bf16.h>
#include <float.h>
#include <math.h>

// Problem constants (from reference)
#define NN 20000
#define EE 320000
#define IN_DIM 128
#define SLOPE_ 0.2f

typedef __attribute__((ext_vector_type(8))) short bf16x8;
typedef __attribute__((ext_vector_type(4))) float f32x4;
typedef _Float16 f16;
typedef __attribute__((ext_vector_type(2))) _Float16 f16x2;
typedef __attribute__((ext_vector_type(8))) _Float16 f16x8;
typedef unsigned short ushort;
typedef __attribute__((ext_vector_type(8))) unsigned short ushort8;

// ---------- bf16 helpers ----------
__device__ inline ushort f32_to_bf16_rn(float f) {
    unsigned u = __float_as_uint(f);
    unsigned rounding = 0x7FFFu + ((u >> 16) & 1u);
    return (ushort)((u + rounding) >> 16);
}
__device__ inline float bf16u_to_f32(ushort h) {
    return __uint_as_float(((unsigned)h) << 16);
}

// ---------- weight prep element: concat + transpose + split ----------
__device__ inline void prep_elem(const float* __restrict__ Wa, const float* __restrict__ ba, int na,
                                 const float* __restrict__ Wb, const float* __restrict__ bb, int nb,
                                 const float* __restrict__ Wc, const float* __restrict__ bc, int nc,
                                 int K, ushort* __restrict__ Wth, ushort* __restrict__ Wtl,
                                 float* __restrict__ bias_cat, int idx) {
    int n = idx / K;
    int k = idx - n * K;
    const float* W; const float* b; int nl; int ncols;
    if (n < na) { W = Wa; b = ba; nl = n; ncols = na; }
    else if (n < na + nb) { W = Wb; b = bb; nl = n - na; ncols = nb; }
    else { W = Wc; b = bc; nl = n - na - nb; ncols = nc; }
    float v = W[(size_t)k * ncols + nl];
    ushort h = f32_to_bf16_rn(v);
    ushort l = f32_to_bf16_rn(v - bf16u_to_f32(h));
    Wth[(size_t)n * K + k] = h;
    Wtl[(size_t)n * K + k] = l;
    if (k == 0) bias_cat[n] = b[nl];
}

// ---------- one launch: all 3 weight preps + x split ----------
#define SEG0 (512 * 128)
#define SEG1 (512 * 256)
#define SEG2 (576 * 256)
#define SEG3 (NN * IN_DIM / 4)
__global__ void prep_all(const float* __restrict__ W0s, const float* __restrict__ b0s,
                         const float* __restrict__ W0d, const float* __restrict__ b0d,
                         const float* __restrict__ W1s, const float* __restrict__ b1s,
                         const float* __restrict__ W1d, const float* __restrict__ b1d,
                         const float* __restrict__ W2s, const float* __restrict__ b2s,
                         const float* __restrict__ W2d, const float* __restrict__ b2d,
                         const float* __restrict__ Wr2, const float* __restrict__ br2,
                         const float* __restrict__ x,
                         ushort* __restrict__ Wt0h, ushort* __restrict__ Wt0l, float* __restrict__ bias0,
                         ushort* __restrict__ Wt1h, ushort* __restrict__ Wt1l, float* __restrict__ bias1,
                         ushort* __restrict__ Wt2h, ushort* __restrict__ Wt2l, float* __restrict__ bias2,
                         ushort* __restrict__ Ah, ushort* __restrict__ Al) {
    int idx = blockIdx.x * 256 + threadIdx.x;
    if (idx < SEG0) {
        prep_elem(W0s, b0s, 256, W0d, b0d, 256, nullptr, nullptr, 0, 128, Wt0h, Wt0l, bias0, idx);
    } else if ((idx -= SEG0) < SEG1) {
        prep_elem(W1s, b1s, 256, W1d, b1d, 256, nullptr, nullptr, 0, 256, Wt1h, Wt1l, bias1, idx);
    } else if ((idx -= SEG1) < SEG2) {
        prep_elem(W2s, b2s, 192, W2d, b2d, 192, Wr2, br2, 192, 256, Wt2h, Wt2l, bias2, idx);
    } else if ((idx -= SEG2) < SEG3) {
        float4 v = ((const float4*)x)[idx];
        ushort h0 = f32_to_bf16_rn(v.x), h1 = f32_to_bf16_rn(v.y);
        ushort h2 = f32_to_bf16_rn(v.z), h3 = f32_to_bf16_rn(v.w);
        ushort l0 = f32_to_bf16_rn(v.x - bf16u_to_f32(h0));
        ushort l1 = f32_to_bf16_rn(v.y - bf16u_to_f32(h1));
        ushort l2 = f32_to_bf16_rn(v.z - bf16u_to_f32(h2));
        ushort l3 = f32_to_bf16_rn(v.w - bf16u_to_f32(h3));
        ((ushort4*)Ah)[idx] = make_ushort4(h0, h1, h2, h3);
        ((ushort4*)Al)[idx] = make_ushort4(l0, l1, l2, l3);
    }
}

// ---------- split-bf16 MFMA GEMM, XCD swizzle, BK=32 (R13) + coalesced f16 epilogue ----------
// BM=128 (4 waves x 32 rows), BN=64, BK=32. Epilogue stages each wave's 32x64 f16
// C-tile in a private LDS region (stride 66 to de-align banks; NO barrier — intra-wave
// ds_write -> ds_read), then writes full 128B row-lines (lane = 64B f16x8 x4).
// Cols [0,b1)->F0(f16), [b1,b2)->F1(f16), [b2,S)->F2(f32, scalar path).
#define BSTRIDE 40
__global__ __launch_bounds__(256) void gemm_mfma_split(
        const ushort* __restrict__ Ahi, const ushort* __restrict__ Alo,
        const ushort* __restrict__ Wth, const ushort* __restrict__ Wtl,
        const float* __restrict__ bias,
        f16* __restrict__ F0, f16* __restrict__ F1, float* __restrict__ F2,
        int b1, int b2, int M, int K, int S, int gx, int gy) {
    __shared__ ushort Bs_hi[64 * BSTRIDE];
    __shared__ ushort Bs_lo[64 * BSTRIDE];
    __shared__ f16 Cs[4][32 * 66];   // per-wave C staging, row stride 66

    const int bid = blockIdx.x;
    const int p = bid & 7;          // XCD slot
    const int q = bid >> 3;
    const int bn_i = q % gx;
    const int bm_i = (q / gx) * 8 + p;
    if (bm_i >= gy) return;
    const int bm = bm_i * 128;
    const int bn = bn_i * 64;

    const int tid = threadIdx.x;
    const int wave = tid >> 6;
    const int lane = tid & 63;
    const int m16 = lane & 15;
    const int quad = lane >> 4;

    f32x4 acc[2][4];
    #pragma unroll
    for (int i = 0; i < 2; ++i)
        #pragma unroll
        for (int j = 0; j < 4; ++j) acc[i][j] = (f32x4){0.f, 0.f, 0.f, 0.f};

    const int srow = tid >> 2;
    const int schk = tid & 3;

    for (int k0 = 0; k0 < K; k0 += 32) {
        {
            size_t goff = (size_t)(bn + srow) * K + k0 + schk * 8;
            bf16x8 vh = *(const bf16x8*)(Wth + goff);
            bf16x8 vl = *(const bf16x8*)(Wtl + goff);
            *(bf16x8*)&Bs_hi[srow * BSTRIDE + schk * 8] = vh;
            *(bf16x8*)&Bs_lo[srow * BSTRIDE + schk * 8] = vl;
        }
        bf16x8 ah[2], al[2];
        #pragma unroll
        for (int mt = 0; mt < 2; ++mt) {
            int row = bm + wave * 32 + mt * 16 + m16;
            row = row < M ? row : M - 1;
            size_t goff = (size_t)row * K + k0 + quad * 8;
            ah[mt] = *(const bf16x8*)(Ahi + goff);
            al[mt] = *(const bf16x8*)(Alo + goff);
        }
        __syncthreads();
        #pragma unroll
        for (int nt = 0; nt < 4; ++nt) {
            int boff = (nt * 16 + m16) * BSTRIDE + quad * 8;
            bf16x8 bh = *(const bf16x8*)&Bs_hi[boff];
            bf16x8 bl = *(const bf16x8*)&Bs_lo[boff];
            #pragma unroll
            for (int mt = 0; mt < 2; ++mt) {
                acc[mt][nt] = __builtin_amdgcn_mfma_f32_16x16x32_bf16(ah[mt], bh, acc[mt][nt], 0, 0, 0);
                acc[mt][nt] = __builtin_amdgcn_mfma_f32_16x16x32_bf16(ah[mt], bl, acc[mt][nt], 0, 0, 0);
                acc[mt][nt] = __builtin_amdgcn_mfma_f32_16x16x32_bf16(al[mt], bh, acc[mt][nt], 0, 0, 0);
            }
        }
        __syncthreads();
    }

    // ---- epilogue ----
    if (bn < b2) {
        // f16 output tile (whole 64-col tile is in one buffer: b1/b2 are x64)
        f16* __restrict__ Fb;
        int cs, cb;
        if (bn >= b1) { Fb = F1; cb = bn - b1; cs = b2 - b1; }
        else          { Fb = F0; cb = bn;      cs = b1; }
        f16* cw = &Cs[wave][0];
        #pragma unroll
        for (int nt = 0; nt < 4; ++nt) {
            float bv = bias[bn + nt * 16 + m16];
            #pragma unroll
            for (int mt = 0; mt < 2; ++mt)
                #pragma unroll
                for (int r = 0; r < 4; ++r) {
                    int row = mt * 16 + quad * 4 + r;   // 0..31 within wave
                    cw[row * 66 + nt * 16 + m16] = (f16)(acc[mt][nt][r] + bv);
                }
        }
        // intra-wave handoff (compiler inserts lgkmcnt); full-line coalesced writes
        int lrow = lane >> 1;
        int lcol = (lane & 1) * 32;
        int grow = bm + wave * 32 + lrow;
        if (grow < M) {
            #pragma unroll
            for (int j = 0; j < 4; ++j) {
                f16x8 v = *(f16x8*)&cw[lrow * 66 + lcol + j * 8];
                *(f16x8*)&Fb[(size_t)grow * cs + cb + lcol + j * 8] = v;
            }
        }
    } else {
        // fp32 residual tile (L2 only): original scalar path
        int cs = S - b2;
        #pragma unroll
        for (int nt = 0; nt < 4; ++nt) {
            int col = bn - b2 + nt * 16 + m16;
            float bv = bias[bn + nt * 16 + m16];
            #pragma unroll
            for (int mt = 0; mt < 2; ++mt)
                #pragma unroll
                for (int r = 0; r < 4; ++r) {
                    int row = bm + wave * 32 + mt * 16 + quad * 4 + r;
                    if (row < M) F2[(size_t)row * cs + col] = acc[mt][nt][r] + bv;
                }
        }
    }
}

// ---------- CSR build ----------
__global__ void zero_u32(unsigned int* __restrict__ p, int n) {
    int i = blockIdx.x * blockDim.x + threadIdx.x;
    if (i < n) p[i] = 0u;
}

__global__ void hist_dst(const int* __restrict__ dst, unsigned int* __restrict__ deg, int E) {
    int e = blockIdx.x * blockDim.x + threadIdx.x;
    if (e < E) atomicAdd(&deg[dst[e]], 1u);
}

__global__ void scan_deg(const unsigned int* __restrict__ deg,
                         unsigned int* __restrict__ row_ptr,
                         unsigned int* __restrict__ cursor, int n) {
    __shared__ unsigned int sums[1024];
    const int t = threadIdx.x;
    const int chunk = (n + 1023) / 1024;
    const int start = t * chunk;
    const int end = min(start + chunk, n);
    unsigned int s = 0;
    for (int i = start; i < end; ++i) s += deg[i];
    sums[t] = s;
    __syncthreads();
    for (int off = 1; off < 1024; off <<= 1) {
        unsigned int v = (t >= off) ? sums[t - off] : 0u;
        __syncthreads();
        sums[t] += v;
        __syncthreads();
    }
    unsigned int prefix = (t == 0) ? 0u : sums[t - 1];
    for (int i = start; i < end; ++i) {
        row_ptr[i] = prefix;
        cursor[i] = prefix;
        prefix += deg[i];
    }
    if (t == 1023) row_ptr[n] = sums[1023];
}

__global__ void scatter_edges(const int* __restrict__ src, const int* __restrict__ dst,
                              unsigned int* __restrict__ cursor,
                              int* __restrict__ csr_src, int E) {
    int e = blockIdx.x * blockDim.x + threadIdx.x;
    if (e < E) {
        unsigned int pos = atomicAdd(&cursor[dst[e]], 1u);
        csr_src[pos] = src[e];
    }
}

// ---------- fused GATv2 aggregate: 2 nodes per wave, 8 f16 dims per lane ----------
// Logit dot in packed f16 (v_pk_add_f16 + |x| via and-mask + v_dot2_f32_f16).
// Plain exp-sum (logits bounded). Scalar per-position clamped index prefetch.
// OUT_MODE: 0 = fp32 out + bf16 hi/lo; 1 = bf16 hi/lo only; 2 = head-mean -> out[N,32].
template <int HD, int D, bool HAS_RES, bool DO_ELU, int OUT_MODE>
__global__ __launch_bounds__(256) void gat_node_aggregate(
        const f16* __restrict__ fsb, const f16* __restrict__ fdb,
        const float* __restrict__ attn,
        const unsigned int* __restrict__ row_ptr,
        const int* __restrict__ csr_src,
        const float* __restrict__ resid, int RS,
        float* __restrict__ outF, ushort* __restrict__ outH, ushort* __restrict__ outL) {
    constexpr int LANES = HD / 8;   // active lanes per node (32 or 24)
    constexpr int GSZ = D / 8;      // lanes per head group (8 or 4)
    __shared__ float red[(OUT_MODE == 2) ? 8 : 1][(OUT_MODE == 2) ? HD : 1];

    const int wave = threadIdx.x >> 6;
    const int lane = threadIdx.x & 63;
    const int half = lane >> 5;            // 0 = node A, 1 = node B
    const int ln = lane & 31;              // lane within node
    const int t = blockIdx.x * 8 + wave * 2 + half;
    const bool active = (ln < LANES);
    const unsigned off = active ? 8u * ln : 0u;   // inactive lanes alias dims 0-7

    f16x2 fdp[4], a6p[4], a4p[4];
    if (active) {
        f16x8 dv = *(const f16x8*)&fdb[(unsigned)t * HD + off];
        float4 aA = *(const float4*)&attn[off];
        float4 aB = *(const float4*)&attn[off + 4];
        float av[8] = {aA.x, aA.y, aA.z, aA.w, aB.x, aB.y, aB.z, aB.w};
        #pragma unroll
        for (int i = 0; i < 4; ++i) {
            fdp[i] = (f16x2){dv[2 * i], dv[2 * i + 1]};
            a6p[i] = (f16x2){(f16)(0.6f * av[2 * i]), (f16)(0.6f * av[2 * i + 1])};
            a4p[i] = (f16x2){(f16)(0.4f * av[2 * i]), (f16)(0.4f * av[2 * i + 1])};
        }
    } else {
        #pragma unroll
        for (int i = 0; i < 4; ++i) {
            fdp[i] = (f16x2){0, 0};
            a6p[i] = (f16x2){0, 0};
            a4p[i] = (f16x2){0, 0};
        }
    }

    const int jj0 = (int)row_ptr[t];
    const int jj1 = (int)row_ptr[t + 1];
    const int deg = jj1 - jj0;
    const int last = jj1 - 1;
    const int degO = __shfl_xor(deg, 32, 64);
    const int mdeg = max(deg, degO);       // wave-uniform loop bound

    float acc[8];
    #pragma unroll
    for (int d = 0; d < 8; ++d) acc[d] = 0.f;
    float lh = 0.f;

    // prologue: features for edges 0..7, indices for refill edges 8..15 (all clamped)
    f16x8 buf[8];
    int cidx[8];
    #pragma unroll
    for (int u = 0; u < 8; ++u) {
        int e0 = min(jj0 + u, last);
        buf[u] = *(const f16x8*)&fsb[(unsigned)csr_src[e0] * HD + off];
        cidx[u] = csr_src[min(jj0 + 8 + u, last)];
    }

    for (int b = 0; b < mdeg; b += 8) {
        // indices for NEXT batch's refills (edges b+16..b+23), clamped per position
        int nidx[8];
        #pragma unroll
        for (int u = 0; u < 8; ++u)
            nidx[u] = csr_src[min(jj0 + b + 16 + u, last)];
        #pragma unroll
        for (int u = 0; u < 8; ++u) {
            const f16x8 cur = buf[u];
            buf[u] = *(const f16x8*)&fsb[(unsigned)cidx[u] * HD + off];  // edge b+8+u
            // packed-f16 logit dot: p = sum x*(0.6a) + |x|*(0.4a), f32 accumulate
            float p = 0.f;
            #pragma unroll
            for (int i = 0; i < 4; ++i) {
                f16x2 cp = (f16x2){cur[2 * i], cur[2 * i + 1]};
                f16x2 xp = cp + fdp[i];                       // v_pk_add_f16
                unsigned xu = __builtin_bit_cast(unsigned, xp) & 0x7FFF7FFFu;
                f16x2 xa = __builtin_bit_cast(f16x2, xu);     // packed |x|
                p = __builtin_amdgcn_fdot2(xp, a6p[i], p, false);
                p = __builtin_amdgcn_fdot2(xa, a4p[i], p, false);
            }
            #pragma unroll
            for (int o = 1; o < GSZ; o <<= 1)
                p += __shfl_xor(p, o, 64);
            float w = (b + u < deg) ? __expf(p) : 0.f;
            lh += w;
            #pragma unroll
            for (int d = 0; d < 8; ++d) acc[d] += w * (float)cur[d];   // fma_mix
        }
        #pragma unroll
        for (int u = 0; u < 8; ++u) cidx[u] = nidx[u];
    }

    float inv = (lh > 0.f) ? 1.f / lh : 0.f;
    float vout[8];
    #pragma unroll
    for (int d = 0; d < 8; ++d) vout[d] = acc[d] * inv;
    if (HAS_RES && active) {
        float4 rA = *(const float4*)&resid[(unsigned)t * RS + off];
        float4 rB = *(const float4*)&resid[(unsigned)t * RS + off + 4];
        vout[0] += rA.x; vout[1] += rA.y; vout[2] += rA.z; vout[3] += rA.w;
        vout[4] += rB.x; vout[5] += rB.y; vout[6] += rB.z; vout[7] += rB.w;
    }
    if (DO_ELU) {
        #pragma unroll
        for (int d = 0; d < 8; ++d) vout[d] = vout[d] > 0.f ? vout[d] : expm1f(vout[d]);
    }

    if (OUT_MODE == 2) {
        const int nib = wave * 2 + half;
        if (active) {
            *(float4*)&red[nib][off] = make_float4(vout[0], vout[1], vout[2], vout[3]);
            *(float4*)&red[nib][off + 4] = make_float4(vout[4], vout[5], vout[6], vout[7]);
        }
        __syncthreads();
        // 8 nodes x 32 cols = 256 threads
        int node = threadIdx.x >> 5;
        int col = threadIdx.x & 31;
        float ssum = 0.f;
        #pragma unroll
        for (int h = 0; h < 6; ++h) ssum += red[node][h * 32 + col];
        outF[(unsigned)(blockIdx.x * 8 + node) * 32 + col] = ssum * (1.f / 6.f);
    } else if (active) {
        ushort8 hv, lv;
        #pragma unroll
        for (int d = 0; d < 8; ++d) {
            ushort h = f32_to_bf16_rn(vout[d]);
            hv[d] = h;
            lv[d] = f32_to_bf16_rn(vout[d] - bf16u_to_f32(h));
        }
        *(ushort8*)&outH[(unsigned)t * HD + off] = hv;
        *(ushort8*)&outL[(unsigned)t * HD + off] = lv;
        if (OUT_MODE == 0) {
            *(float4*)&outF[(unsigned)t * HD + off] = make_float4(vout[0], vout[1], vout[2], vout[3]);
            *(float4*)&outF[(unsigned)t * HD + off + 4] = make_float4(vout[4], vout[5], vout[6], vout[7]);
        }
    }
}

extern "C" void kernel_launch(void* const* d_in, const int* in_sizes, int n_in,
                              void* d_out, int out_size, void* d_ws, size_t ws_size,
                              hipStream_t stream) {
    const float* x   = (const float*)d_in[0];
    const int*   src = (const int*)d_in[1];
    const int*   dst = (const int*)d_in[2];
    const float* W0s = (const float*)d_in[3];
    const float* b0s = (const float*)d_in[4];
    const float* W0d = (const float*)d_in[5];
    const float* b0d = (const float*)d_in[6];
    const float* a0  = (const float*)d_in[7];
    const float* W1s = (const float*)d_in[8];
    const float* b1s = (const float*)d_in[9];
    const float* W1d = (const float*)d_in[10];
    const float* b1d = (const float*)d_in[11];
    const float* a1  = (const float*)d_in[12];
    const float* W2s = (const float*)d_in[13];
    const float* b2s = (const float*)d_in[14];
    const float* W2d = (const float*)d_in[15];
    const float* b2d = (const float*)d_in[16];
    const float* a2  = (const float*)d_in[17];
    const float* Wr2 = (const float*)d_in[18];
    const float* br2 = (const float*)d_in[19];

    // ---- workspace layout ----
    f16* FsH = (f16*)d_ws;                           // N*256 f16 (fs, dense gather target)
    f16* FdH = FsH + (size_t)NN * 256;               // N*256 f16 (fd)
    float* O0 = (float*)(FdH + (size_t)NN * 256);    // N*256 fp32 (L1 residual; later L2 Fr N*192)
    ushort* Ah = (ushort*)(O0 + (size_t)NN * 256);   // N*256 bf16
    ushort* Al = Ah + (size_t)NN * 256;              // N*256
    ushort* Wt0h = Al + (size_t)NN * 256;            // 512*128
    ushort* Wt0l = Wt0h + 512 * 128;
    ushort* Wt1h = Wt0l + 512 * 128;                 // 512*256
    ushort* Wt1l = Wt1h + 512 * 256;
    ushort* Wt2h = Wt1l + 512 * 256;                 // 576*256
    ushort* Wt2l = Wt2h + 576 * 256;
    float* bias0 = (float*)(Wt2l + 576 * 256);       // 512
    float* bias1 = bias0 + 512;                      // 512
    float* bias2 = bias1 + 512;                      // 576
    unsigned int* row_ptr = (unsigned int*)(bias2 + 576);  // N+1
    unsigned int* cursor  = row_ptr + (NN + 1);
    unsigned int* deg     = cursor + NN;
    int* csr_src          = (int*)(deg + NN);        // E

    // ---- build CSR ----
    zero_u32<<<(NN + 255) / 256, 256, 0, stream>>>(deg, NN);
    hist_dst<<<(EE + 255) / 256, 256, 0, stream>>>(dst, deg, EE);
    scan_deg<<<1, 1024, 0, stream>>>(deg, row_ptr, cursor, NN);
    scatter_edges<<<(EE + 255) / 256, 256, 0, stream>>>(src, dst, cursor, csr_src, EE);

    // ---- all weight prep + x split in ONE launch ----
    {
        int total = SEG0 + SEG1 + SEG2 + SEG3;
        prep_all<<<(total + 255) / 256, 256, 0, stream>>>(
            W0s, b0s, W0d, b0d, W1s, b1s, W1d, b1d, W2s, b2s, W2d, b2d, Wr2, br2, x,
            Wt0h, Wt0l, bias0, Wt1h, Wt1l, bias1, Wt2h, Wt2l, bias2, Ah, Al);
    }

    const int gy = (NN + 127) / 128;           // 157 bm tiles
    const int gy8 = ((gy + 7) / 8) * 8;        // 160 (rounded for swizzle)
    const int nagg = NN / 8;                   // 2500 blocks, 8 nodes each (2 per wave)

    // ---- layer 0: x[N,128] -> FsH/FdH[N,256] f16 -> O0 fp32 + Ah/Al bf16 ----
    gemm_mfma_split<<<gy8 * 8, 256, 0, stream>>>(Ah, Al, Wt0h, Wt0l, bias0,
                                                 FsH, FdH, nullptr, 256, 512, NN, 128, 512, 8, gy);
    gat_node_aggregate<256, 64, false, true, 0><<<nagg, 256, 0, stream>>>(
        FsH, FdH, a0, row_ptr, csr_src, nullptr, 0, O0, Ah, Al);

    // ---- layer 1: Ah/Al -> FsH/FdH[N,256] -> Ah/Al (identity residual O0 fp32) ----
    gemm_mfma_split<<<gy8 * 8, 256, 0, stream>>>(Ah, Al, Wt1h, Wt1l, bias1,
                                                 FsH, FdH, nullptr, 256, 512, NN, 256, 512, 8, gy);
    gat_node_aggregate<256, 64, true, true, 1><<<nagg, 256, 0, stream>>>(
        FsH, FdH, a1, row_ptr, csr_src, O0, 256, nullptr, Ah, Al);

    // ---- layer 2: Ah/Al -> FsH/FdH[N,192] + Fr(=O0 fp32)[N,192] -> d_out[N,32] ----
    gemm_mfma_split<<<gy8 * 9, 256, 0, stream>>>(Ah, Al, Wt2h, Wt2l, bias2,
                                                 FsH, FdH, O0, 192, 384, NN, 256, 576, 9, gy);
    gat_node_aggregate<192, 32, true, false, 2><<<nagg, 256, 0, stream>>>(
        FsH, FdH, a2, row_ptr, csr_src, O0, 192, (float*)d_out, nullptr, nullptr);
}

// Round 16
// 333.086 us; speedup vs baseline: 1.3595x; 1.1001x over previous
//
#include <hip/hip_runtime.h>
#include <hip/hip_bf16.h>
#include <float.h>
#include <math.h>

// Problem constants (from reference)
#define NN 20000
#define EE 320000
#define IN_DIM 128
#define SLOPE_ 0.2f

typedef __attribute__((ext_vector_type(4))) float f32x4;
typedef _Float16 f16;
typedef __attribute__((ext_vector_type(2))) _Float16 f16x2;
typedef __attribute__((ext_vector_type(4))) _Float16 f16x4;
typedef __attribute__((ext_vector_type(8))) _Float16 f16x8;
typedef unsigned short ushort;

// ---------- weight prep element: concat + transpose, single f16 ----------
__device__ inline void prep_elem(const float* __restrict__ Wa, const float* __restrict__ ba, int na,
                                 const float* __restrict__ Wb, const float* __restrict__ bb, int nb,
                                 const float* __restrict__ Wc, const float* __restrict__ bc, int nc,
                                 int K, f16* __restrict__ Wt, float* __restrict__ bias_cat, int idx) {
    int n = idx / K;
    int k = idx - n * K;
    const float* W; const float* b; int nl; int ncols;
    if (n < na) { W = Wa; b = ba; nl = n; ncols = na; }
    else if (n < na + nb) { W = Wb; b = bb; nl = n - na; ncols = nb; }
    else { W = Wc; b = bc; nl = n - na - nb; ncols = nc; }
    Wt[(size_t)n * K + k] = (f16)W[(size_t)k * ncols + nl];
    if (k == 0) bias_cat[n] = b[nl];
}

// ---------- one launch: all 3 weight preps + x -> f16 ----------
#define SEG0 (512 * 128)
#define SEG1 (512 * 256)
#define SEG2 (576 * 256)
#define SEG3 (NN * IN_DIM / 4)
__global__ void prep_all(const float* __restrict__ W0s, const float* __restrict__ b0s,
                         const float* __restrict__ W0d, const float* __restrict__ b0d,
                         const float* __restrict__ W1s, const float* __restrict__ b1s,
                         const float* __restrict__ W1d, const float* __restrict__ b1d,
                         const float* __restrict__ W2s, const float* __restrict__ b2s,
                         const float* __restrict__ W2d, const float* __restrict__ b2d,
                         const float* __restrict__ Wr2, const float* __restrict__ br2,
                         const float* __restrict__ x,
                         f16* __restrict__ Wt0, float* __restrict__ bias0,
                         f16* __restrict__ Wt1, float* __restrict__ bias1,
                         f16* __restrict__ Wt2, float* __restrict__ bias2,
                         f16* __restrict__ A) {
    int idx = blockIdx.x * 256 + threadIdx.x;
    if (idx < SEG0) {
        prep_elem(W0s, b0s, 256, W0d, b0d, 256, nullptr, nullptr, 0, 128, Wt0, bias0, idx);
    } else if ((idx -= SEG0) < SEG1) {
        prep_elem(W1s, b1s, 256, W1d, b1d, 256, nullptr, nullptr, 0, 256, Wt1, bias1, idx);
    } else if ((idx -= SEG1) < SEG2) {
        prep_elem(W2s, b2s, 192, W2d, b2d, 192, Wr2, br2, 192, 256, Wt2, bias2, idx);
    } else if ((idx -= SEG2) < SEG3) {
        float4 v = ((const float4*)x)[idx];
        f16x4 o = {(f16)v.x, (f16)v.y, (f16)v.z, (f16)v.w};
        ((f16x4*)A)[idx] = o;
    }
}

// ---------- single-f16 MFMA GEMM, XCD swizzle, BK=32, coalesced f16 epilogue ----------
// BM=128 (4 waves x 32 rows), BN=64, BK=32. 8 MFMA (16x16x32_f16) per k-step.
// Cols [0,b1)->F0(f16), [b1,b2)->F1(f16), [b2,S)->F2(f32, scalar path).
#define BSTRIDE 40
__global__ __launch_bounds__(256) void gemm_mfma_f16(
        const f16* __restrict__ A, const f16* __restrict__ Wt,
        const float* __restrict__ bias,
        f16* __restrict__ F0, f16* __restrict__ F1, float* __restrict__ F2,
        int b1, int b2, int M, int K, int S, int gx, int gy) {
    __shared__ f16 Bs[64 * BSTRIDE];
    __shared__ f16 Cs[4][32 * 66];   // per-wave C staging, row stride 66

    const int bid = blockIdx.x;
    const int p = bid & 7;          // XCD slot
    const int q = bid >> 3;
    const int bn_i = q % gx;
    const int bm_i = (q / gx) * 8 + p;
    if (bm_i >= gy) return;
    const int bm = bm_i * 128;
    const int bn = bn_i * 64;

    const int tid = threadIdx.x;
    const int wave = tid >> 6;
    const int lane = tid & 63;
    const int m16 = lane & 15;
    const int quad = lane >> 4;

    f32x4 acc[2][4];
    #pragma unroll
    for (int i = 0; i < 2; ++i)
        #pragma unroll
        for (int j = 0; j < 4; ++j) acc[i][j] = (f32x4){0.f, 0.f, 0.f, 0.f};

    const int srow = tid >> 2;
    const int schk = tid & 3;

    for (int k0 = 0; k0 < K; k0 += 32) {
        {
            size_t goff = (size_t)(bn + srow) * K + k0 + schk * 8;
            *(f16x8*)&Bs[srow * BSTRIDE + schk * 8] = *(const f16x8*)(Wt + goff);
        }
        f16x8 ah[2];
        #pragma unroll
        for (int mt = 0; mt < 2; ++mt) {
            int row = bm + wave * 32 + mt * 16 + m16;
            row = row < M ? row : M - 1;
            ah[mt] = *(const f16x8*)(A + (size_t)row * K + k0 + quad * 8);
        }
        __syncthreads();
        #pragma unroll
        for (int nt = 0; nt < 4; ++nt) {
            f16x8 bs = *(const f16x8*)&Bs[(nt * 16 + m16) * BSTRIDE + quad * 8];
            #pragma unroll
            for (int mt = 0; mt < 2; ++mt)
                acc[mt][nt] = __builtin_amdgcn_mfma_f32_16x16x32_f16(ah[mt], bs, acc[mt][nt], 0, 0, 0);
        }
        __syncthreads();
    }

    // ---- epilogue ----
    if (bn < b2) {
        // f16 output tile (whole 64-col tile in one buffer: b1/b2 are x64)
        f16* __restrict__ Fb;
        int cs, cb;
        if (bn >= b1) { Fb = F1; cb = bn - b1; cs = b2 - b1; }
        else          { Fb = F0; cb = bn;      cs = b1; }
        f16* cw = &Cs[wave][0];
        #pragma unroll
        for (int nt = 0; nt < 4; ++nt) {
            float bv = bias[bn + nt * 16 + m16];
            #pragma unroll
            for (int mt = 0; mt < 2; ++mt)
                #pragma unroll
                for (int r = 0; r < 4; ++r) {
                    int row = mt * 16 + quad * 4 + r;   // 0..31 within wave
                    cw[row * 66 + nt * 16 + m16] = (f16)(acc[mt][nt][r] + bv);
                }
        }
        // intra-wave handoff; full-line coalesced writes
        int lrow = lane >> 1;
        int lcol = (lane & 1) * 32;
        int grow = bm + wave * 32 + lrow;
        if (grow < M) {
            #pragma unroll
            for (int j = 0; j < 4; ++j) {
                f16x8 v = *(f16x8*)&cw[lrow * 66 + lcol + j * 8];
                *(f16x8*)&Fb[(size_t)grow * cs + cb + lcol + j * 8] = v;
            }
        }
    } else {
        // fp32 residual tile (L2 only): scalar path
        int cs = S - b2;
        #pragma unroll
        for (int nt = 0; nt < 4; ++nt) {
            int col = bn - b2 + nt * 16 + m16;
            float bv = bias[bn + nt * 16 + m16];
            #pragma unroll
            for (int mt = 0; mt < 2; ++mt)
                #pragma unroll
                for (int r = 0; r < 4; ++r) {
                    int row = bm + wave * 32 + mt * 16 + quad * 4 + r;
                    if (row < M) F2[(size_t)row * cs + col] = acc[mt][nt][r] + bv;
                }
        }
    }
}

// ---------- CSR build ----------
__global__ void zero_u32(unsigned int* __restrict__ p, int n) {
    int i = blockIdx.x * blockDim.x + threadIdx.x;
    if (i < n) p[i] = 0u;
}

__global__ void hist_dst(const int* __restrict__ dst, unsigned int* __restrict__ deg, int E) {
    int e = blockIdx.x * blockDim.x + threadIdx.x;
    if (e < E) atomicAdd(&deg[dst[e]], 1u);
}

__global__ void scan_deg(const unsigned int* __restrict__ deg,
                         unsigned int* __restrict__ row_ptr,
                         unsigned int* __restrict__ cursor, int n) {
    __shared__ unsigned int sums[1024];
    const int t = threadIdx.x;
    const int chunk = (n + 1023) / 1024;
    const int start = t * chunk;
    const int end = min(start + chunk, n);
    unsigned int s = 0;
    for (int i = start; i < end; ++i) s += deg[i];
    sums[t] = s;
    __syncthreads();
    for (int off = 1; off < 1024; off <<= 1) {
        unsigned int v = (t >= off) ? sums[t - off] : 0u;
        __syncthreads();
        sums[t] += v;
        __syncthreads();
    }
    unsigned int prefix = (t == 0) ? 0u : sums[t - 1];
    for (int i = start; i < end; ++i) {
        row_ptr[i] = prefix;
        cursor[i] = prefix;
        prefix += deg[i];
    }
    if (t == 1023) row_ptr[n] = sums[1023];
}

__global__ void scatter_edges(const int* __restrict__ src, const int* __restrict__ dst,
                              unsigned int* __restrict__ cursor,
                              int* __restrict__ csr_src, int E) {
    int e = blockIdx.x * blockDim.x + threadIdx.x;
    if (e < E) {
        unsigned int pos = atomicAdd(&cursor[dst[e]], 1u);
        csr_src[pos] = src[e];
    }
}

// ---------- fused GATv2 aggregate: 2 nodes per wave, 8 f16 dims per lane ----------
// Logit dot in packed f16 (v_pk_add_f16 + |x| via and-mask + v_dot2_f32_f16).
// Plain exp-sum (logits bounded). Scalar per-position clamped index prefetch.
// OUT_MODE: 0 = fp32 out + f16 A; 1 = f16 A only; 2 = head-mean -> out[N,32].
template <int HD, int D, bool HAS_RES, bool DO_ELU, int OUT_MODE>
__global__ __launch_bounds__(256) void gat_node_aggregate(
        const f16* __restrict__ fsb, const f16* __restrict__ fdb,
        const float* __restrict__ attn,
        const unsigned int* __restrict__ row_ptr,
        const int* __restrict__ csr_src,
        const float* __restrict__ resid, int RS,
        float* __restrict__ outF, f16* __restrict__ outA) {
    constexpr int LANES = HD / 8;   // active lanes per node (32 or 24)
    constexpr int GSZ = D / 8;      // lanes per head group (8 or 4)
    __shared__ float red[(OUT_MODE == 2) ? 8 : 1][(OUT_MODE == 2) ? HD : 1];

    const int wave = threadIdx.x >> 6;
    const int lane = threadIdx.x & 63;
    const int half = lane >> 5;            // 0 = node A, 1 = node B
    const int ln = lane & 31;              // lane within node
    const int t = blockIdx.x * 8 + wave * 2 + half;
    const bool active = (ln < LANES);
    const unsigned off = active ? 8u * ln : 0u;   // inactive lanes alias dims 0-7

    f16x2 fdp[4], a6p[4], a4p[4];
    if (active) {
        f16x8 dv = *(const f16x8*)&fdb[(unsigned)t * HD + off];
        float4 aA = *(const float4*)&attn[off];
        float4 aB = *(const float4*)&attn[off + 4];
        float av[8] = {aA.x, aA.y, aA.z, aA.w, aB.x, aB.y, aB.z, aB.w};
        #pragma unroll
        for (int i = 0; i < 4; ++i) {
            fdp[i] = (f16x2){dv[2 * i], dv[2 * i + 1]};
            a6p[i] = (f16x2){(f16)(0.6f * av[2 * i]), (f16)(0.6f * av[2 * i + 1])};
            a4p[i] = (f16x2){(f16)(0.4f * av[2 * i]), (f16)(0.4f * av[2 * i + 1])};
        }
    } else {
        #pragma unroll
        for (int i = 0; i < 4; ++i) {
            fdp[i] = (f16x2){0, 0};
            a6p[i] = (f16x2){0, 0};
            a4p[i] = (f16x2){0, 0};
        }
    }

    const int jj0 = (int)row_ptr[t];
    const int jj1 = (int)row_ptr[t + 1];
    const int deg = jj1 - jj0;
    const int last = jj1 - 1;
    const int degO = __shfl_xor(deg, 32, 64);
    const int mdeg = max(deg, degO);       // wave-uniform loop bound

    float acc[8];
    #pragma unroll
    for (int d = 0; d < 8; ++d) acc[d] = 0.f;
    float lh = 0.f;

    // prologue: features for edges 0..7, indices for refill edges 8..15 (all clamped)
    f16x8 buf[8];
    int cidx[8];
    #pragma unroll
    for (int u = 0; u < 8; ++u) {
        int e0 = min(jj0 + u, last);
        buf[u] = *(const f16x8*)&fsb[(unsigned)csr_src[e0] * HD + off];
        cidx[u] = csr_src[min(jj0 + 8 + u, last)];
    }

    for (int b = 0; b < mdeg; b += 8) {
        // indices for NEXT batch's refills (edges b+16..b+23), clamped per position
        int nidx[8];
        #pragma unroll
        for (int u = 0; u < 8; ++u)
            nidx[u] = csr_src[min(jj0 + b + 16 + u, last)];
        #pragma unroll
        for (int u = 0; u < 8; ++u) {
            const f16x8 cur = buf[u];
            buf[u] = *(const f16x8*)&fsb[(unsigned)cidx[u] * HD + off];  // edge b+8+u
            // packed-f16 logit dot: p = sum x*(0.6a) + |x|*(0.4a), f32 accumulate
            float p = 0.f;
            #pragma unroll
            for (int i = 0; i < 4; ++i) {
                f16x2 cp = (f16x2){cur[2 * i], cur[2 * i + 1]};
                f16x2 xp = cp + fdp[i];                       // v_pk_add_f16
                unsigned xu = __builtin_bit_cast(unsigned, xp) & 0x7FFF7FFFu;
                f16x2 xa = __builtin_bit_cast(f16x2, xu);     // packed |x|
                p = __builtin_amdgcn_fdot2(xp, a6p[i], p, false);
                p = __builtin_amdgcn_fdot2(xa, a4p[i], p, false);
            }
            #pragma unroll
            for (int o = 1; o < GSZ; o <<= 1)
                p += __shfl_xor(p, o, 64);
            float w = (b + u < deg) ? __expf(p) : 0.f;
            lh += w;
            #pragma unroll
            for (int d = 0; d < 8; ++d) acc[d] += w * (float)cur[d];   // fma_mix
        }
        #pragma unroll
        for (int u = 0; u < 8; ++u) cidx[u] = nidx[u];
    }

    float inv = (lh > 0.f) ? 1.f / lh : 0.f;
    float vout[8];
    #pragma unroll
    for (int d = 0; d < 8; ++d) vout[d] = acc[d] * inv;
    if (HAS_RES && active) {
        float4 rA = *(const float4*)&resid[(unsigned)t * RS + off];
        float4 rB = *(const float4*)&resid[(unsigned)t * RS + off + 4];
        vout[0] += rA.x; vout[1] += rA.y; vout[2] += rA.z; vout[3] += rA.w;
        vout[4] += rB.x; vout[5] += rB.y; vout[6] += rB.z; vout[7] += rB.w;
    }
    if (DO_ELU) {
        #pragma unroll
        for (int d = 0; d < 8; ++d) vout[d] = vout[d] > 0.f ? vout[d] : expm1f(vout[d]);
    }

    if (OUT_MODE == 2) {
        const int nib = wave * 2 + half;
        if (active) {
            *(float4*)&red[nib][off] = make_float4(vout[0], vout[1], vout[2], vout[3]);
            *(float4*)&red[nib][off + 4] = make_float4(vout[4], vout[5], vout[6], vout[7]);
        }
        __syncthreads();
        // 8 nodes x 32 cols = 256 threads
        int node = threadIdx.x >> 5;
        int col = threadIdx.x & 31;
        float ssum = 0.f;
        #pragma unroll
        for (int h = 0; h < 6; ++h) ssum += red[node][h * 32 + col];
        outF[(unsigned)(blockIdx.x * 8 + node) * 32 + col] = ssum * (1.f / 6.f);
    } else if (active) {
        f16x8 av;
        #pragma unroll
        for (int d = 0; d < 8; ++d) av[d] = (f16)vout[d];
        *(f16x8*)&outA[(unsigned)t * HD + off] = av;
        if (OUT_MODE == 0) {
            *(float4*)&outF[(unsigned)t * HD + off] = make_float4(vout[0], vout[1], vout[2], vout[3]);
            *(float4*)&outF[(unsigned)t * HD + off + 4] = make_float4(vout[4], vout[5], vout[6], vout[7]);
        }
    }
}

extern "C" void kernel_launch(void* const* d_in, const int* in_sizes, int n_in,
                              void* d_out, int out_size, void* d_ws, size_t ws_size,
                              hipStream_t stream) {
    const float* x   = (const float*)d_in[0];
    const int*   src = (const int*)d_in[1];
    const int*   dst = (const int*)d_in[2];
    const float* W0s = (const float*)d_in[3];
    const float* b0s = (const float*)d_in[4];
    const float* W0d = (const float*)d_in[5];
    const float* b0d = (const float*)d_in[6];
    const float* a0  = (const float*)d_in[7];
    const float* W1s = (const float*)d_in[8];
    const float* b1s = (const float*)d_in[9];
    const float* W1d = (const float*)d_in[10];
    const float* b1d = (const float*)d_in[11];
    const float* a1  = (const float*)d_in[12];
    const float* W2s = (const float*)d_in[13];
    const float* b2s = (const float*)d_in[14];
    const float* W2d = (const float*)d_in[15];
    const float* b2d = (const float*)d_in[16];
    const float* a2  = (const float*)d_in[17];
    const float* Wr2 = (const float*)d_in[18];
    const float* br2 = (const float*)d_in[19];

    // ---- workspace layout ----
    f16* FsH = (f16*)d_ws;                           // N*256 f16 (fs, dense gather target)
    f16* FdH = FsH + (size_t)NN * 256;               // N*256 f16 (fd)
    f16* A   = FdH + (size_t)NN * 256;               // N*256 f16 (GEMM A input)
    float* O0 = (float*)(A + (size_t)NN * 256);      // N*256 fp32 (L1 residual; later L2 Fr N*192)
    f16* Wt0 = (f16*)(O0 + (size_t)NN * 256);        // 512*128
    f16* Wt1 = Wt0 + 512 * 128;                      // 512*256
    f16* Wt2 = Wt1 + 512 * 256;                      // 576*256
    float* bias0 = (float*)(Wt2 + 576 * 256);        // 512
    float* bias1 = bias0 + 512;                      // 512
    float* bias2 = bias1 + 512;                      // 576
    unsigned int* row_ptr = (unsigned int*)(bias2 + 576);  // N+1
    unsigned int* cursor  = row_ptr + (NN + 1);
    unsigned int* deg     = cursor + NN;
    int* csr_src          = (int*)(deg + NN);        // E

    // ---- build CSR ----
    zero_u32<<<(NN + 255) / 256, 256, 0, stream>>>(deg, NN);
    hist_dst<<<(EE + 255) / 256, 256, 0, stream>>>(dst, deg, EE);
    scan_deg<<<1, 1024, 0, stream>>>(deg, row_ptr, cursor, NN);
    scatter_edges<<<(EE + 255) / 256, 256, 0, stream>>>(src, dst, cursor, csr_src, EE);

    // ---- all weight prep + x -> f16 in ONE launch ----
    {
        int total = SEG0 + SEG1 + SEG2 + SEG3;
        prep_all<<<(total + 255) / 256, 256, 0, stream>>>(
            W0s, b0s, W0d, b0d, W1s, b1s, W1d, b1d, W2s, b2s, W2d, b2d, Wr2, br2, x,
            Wt0, bias0, Wt1, bias1, Wt2, bias2, A);
    }

    const int gy = (NN + 127) / 128;           // 157 bm tiles
    const int gy8 = ((gy + 7) / 8) * 8;        // 160 (rounded for swizzle)
    const int nagg = NN / 8;                   // 2500 blocks, 8 nodes each (2 per wave)

    // ---- layer 0: A(x f16)[N,128] -> FsH/FdH[N,256] -> O0 fp32 + A f16 ----
    gemm_mfma_f16<<<gy8 * 8, 256, 0, stream>>>(A, Wt0, bias0,
                                               FsH, FdH, nullptr, 256, 512, NN, 128, 512, 8, gy);
    gat_node_aggregate<256, 64, false, true, 0><<<nagg, 256, 0, stream>>>(
        FsH, FdH, a0, row_ptr, csr_src, nullptr, 0, O0, A);

    // ---- layer 1: A -> FsH/FdH[N,256] -> A (identity residual O0 fp32) ----
    gemm_mfma_f16<<<gy8 * 8, 256, 0, stream>>>(A, Wt1, bias1,
                                               FsH, FdH, nullptr, 256, 512, NN, 256, 512, 8, gy);
    gat_node_aggregate<256, 64, true, true, 1><<<nagg, 256, 0, stream>>>(
        FsH, FdH, a1, row_ptr, csr_src, O0, 256, nullptr, A);

    // ---- layer 2: A -> FsH/FdH[N,192] + Fr(=O0 fp32)[N,192] -> d_out[N,32] ----
    gemm_mfma_f16<<<gy8 * 9, 256, 0, stream>>>(A, Wt2, bias2,
                                               FsH, FdH, O0, 192, 384, NN, 256, 576, 9, gy);
    gat_node_aggregate<192, 32, true, false, 2><<<nagg, 256, 0, stream>>>(
        FsH, FdH, a2, row_ptr, csr_src, O0, 192, (float*)d_out, nullptr);
}

// Round 17
// 330.619 us; speedup vs baseline: 1.3696x; 1.0075x over previous
//
#include <hip/hip_runtime.h>
#include <hip/hip_bf16.h>
#include <float.h>
#include <math.h>

// Problem constants (from reference)
#define NN 20000
#define EE 320000
#define IN_DIM 128
#define SLOPE_ 0.2f

typedef __attribute__((ext_vector_type(4))) float f32x4;
typedef _Float16 f16;
typedef __attribute__((ext_vector_type(2))) _Float16 f16x2;
typedef __attribute__((ext_vector_type(4))) _Float16 f16x4;
typedef __attribute__((ext_vector_type(8))) _Float16 f16x8;
typedef unsigned short ushort;

// ---------- weight prep element: concat + transpose, single f16 ----------
__device__ inline void prep_elem(const float* __restrict__ Wa, const float* __restrict__ ba, int na,
                                 const float* __restrict__ Wb, const float* __restrict__ bb, int nb,
                                 const float* __restrict__ Wc, const float* __restrict__ bc, int nc,
                                 int K, f16* __restrict__ Wt, float* __restrict__ bias_cat, int idx) {
    int n = idx / K;
    int k = idx - n * K;
    const float* W; const float* b; int nl; int ncols;
    if (n < na) { W = Wa; b = ba; nl = n; ncols = na; }
    else if (n < na + nb) { W = Wb; b = bb; nl = n - na; ncols = nb; }
    else { W = Wc; b = bc; nl = n - na - nb; ncols = nc; }
    Wt[(size_t)n * K + k] = (f16)W[(size_t)k * ncols + nl];
    if (k == 0) bias_cat[n] = b[nl];
}

// ---------- one launch: all 3 weight preps + x -> f16 ----------
#define SEG0 (512 * 128)
#define SEG1 (512 * 256)
#define SEG2 (576 * 256)
#define SEG3 (NN * IN_DIM / 4)
__global__ void prep_all(const float* __restrict__ W0s, const float* __restrict__ b0s,
                         const float* __restrict__ W0d, const float* __restrict__ b0d,
                         const float* __restrict__ W1s, const float* __restrict__ b1s,
                         const float* __restrict__ W1d, const float* __restrict__ b1d,
                         const float* __restrict__ W2s, const float* __restrict__ b2s,
                         const float* __restrict__ W2d, const float* __restrict__ b2d,
                         const float* __restrict__ Wr2, const float* __restrict__ br2,
                         const float* __restrict__ x,
                         f16* __restrict__ Wt0, float* __restrict__ bias0,
                         f16* __restrict__ Wt1, float* __restrict__ bias1,
                         f16* __restrict__ Wt2, float* __restrict__ bias2,
                         f16* __restrict__ A) {
    int idx = blockIdx.x * 256 + threadIdx.x;
    if (idx < SEG0) {
        prep_elem(W0s, b0s, 256, W0d, b0d, 256, nullptr, nullptr, 0, 128, Wt0, bias0, idx);
    } else if ((idx -= SEG0) < SEG1) {
        prep_elem(W1s, b1s, 256, W1d, b1d, 256, nullptr, nullptr, 0, 256, Wt1, bias1, idx);
    } else if ((idx -= SEG1) < SEG2) {
        prep_elem(W2s, b2s, 192, W2d, b2d, 192, Wr2, br2, 192, 256, Wt2, bias2, idx);
    } else if ((idx -= SEG2) < SEG3) {
        float4 v = ((const float4*)x)[idx];
        f16x4 o = {(f16)v.x, (f16)v.y, (f16)v.z, (f16)v.w};
        ((f16x4*)A)[idx] = o;
    }
}

// ---------- single-f16 MFMA GEMM v2: B-slice resident in LDS, ONE barrier total ----------
// Block = 256 rows (4 waves x 64) x 64 cols. B (64 x K f16, <=32 KB) staged once in
// MFMA-fragment order: chunk[(k0/32)*4+nt][lane] = Wt[bn+nt*16+(lane&15)][k0+(lane>>4)*8..+8]
// -> every ds_read_b128 is lane*16B consecutive (conflict-free). After the single
// __syncthreads, waves stream their rows independently: 2 A-frag loads + 4 LDS reads
// + 8 MFMA per k-step, no further sync. Coalesced f16 epilogue via per-wave Cs.
// Cols [0,b1)->F0(f16), [b1,b2)->F1(f16), [b2,S)->F2(f32, scalar path).
__global__ __launch_bounds__(256) void gemm_mfma_f16(
        const f16* __restrict__ A, const f16* __restrict__ Wt,
        const float* __restrict__ bias,
        f16* __restrict__ F0, f16* __restrict__ F1, float* __restrict__ F2,
        int b1, int b2, int M, int K, int S, int gx, int gy) {
    __shared__ f16 Bs[64 * 256];     // up to 32 KB, swizzled fragment order
    __shared__ f16 Cs[4][32 * 66];   // per-wave C staging, row stride 66

    const int bid = blockIdx.x;
    const int p = bid & 7;          // XCD slot
    const int q = bid >> 3;
    const int bn_i = q % gx;
    const int bm_i = (q / gx) * 8 + p;
    if (bm_i >= gy) return;
    const int bm = bm_i * 256;
    const int bn = bn_i * 64;

    const int tid = threadIdx.x;
    const int wave = tid >> 6;
    const int lane = tid & 63;
    const int m16 = lane & 15;
    const int quad = lane >> 4;

    // ---- stage whole B slice to LDS in fragment order ----
    {
        const int n = tid >> 2;      // 0..63 output col within tile
        const int q0 = tid & 3;      // quad of the 32-k chunk
        for (int j = 0; j * 32 < K; ++j) {
            int k0 = j * 32 + q0 * 8;
            f16x8 v = *(const f16x8*)(Wt + (size_t)(bn + n) * K + k0);
            int chunk = (j * 4 + (n >> 4)) * 64 + q0 * 16 + (n & 15);
            *(f16x8*)&Bs[chunk * 8] = v;
        }
    }
    __syncthreads();   // the ONLY barrier

    #pragma unroll
    for (int miter = 0; miter < 2; ++miter) {
        const int rbase = bm + wave * 64 + miter * 32;
        f32x4 acc[2][4];
        #pragma unroll
        for (int i = 0; i < 2; ++i)
            #pragma unroll
            for (int j = 0; j < 4; ++j) acc[i][j] = (f32x4){0.f, 0.f, 0.f, 0.f};

        int ar[2];
        #pragma unroll
        for (int mt = 0; mt < 2; ++mt) {
            int row = rbase + mt * 16 + m16;
            ar[mt] = row < M ? row : M - 1;
        }

        #pragma unroll 4
        for (int k0 = 0; k0 < K; k0 += 32) {
            f16x8 ah[2];
            #pragma unroll
            for (int mt = 0; mt < 2; ++mt)
                ah[mt] = *(const f16x8*)(A + (size_t)ar[mt] * K + k0 + quad * 8);
            #pragma unroll
            for (int nt = 0; nt < 4; ++nt) {
                f16x8 bs = *(const f16x8*)&Bs[(((k0 >> 5) * 4 + nt) * 64 + lane) * 8];
                #pragma unroll
                for (int mt = 0; mt < 2; ++mt)
                    acc[mt][nt] = __builtin_amdgcn_mfma_f32_16x16x32_f16(ah[mt], bs, acc[mt][nt], 0, 0, 0);
            }
        }

        // ---- epilogue for this miter ----
        if (bn < b2) {
            f16* __restrict__ Fb;
            int cs, cb;
            if (bn >= b1) { Fb = F1; cb = bn - b1; cs = b2 - b1; }
            else          { Fb = F0; cb = bn;      cs = b1; }
            f16* cw = &Cs[wave][0];
            #pragma unroll
            for (int nt = 0; nt < 4; ++nt) {
                float bv = bias[bn + nt * 16 + m16];
                #pragma unroll
                for (int mt = 0; mt < 2; ++mt)
                    #pragma unroll
                    for (int r = 0; r < 4; ++r) {
                        int row = mt * 16 + quad * 4 + r;   // 0..31 within miter
                        cw[row * 66 + nt * 16 + m16] = (f16)(acc[mt][nt][r] + bv);
                    }
            }
            // intra-wave handoff; full-line coalesced writes
            int lrow = lane >> 1;
            int lcol = (lane & 1) * 32;
            int grow = rbase + lrow;
            if (grow < M) {
                #pragma unroll
                for (int j = 0; j < 4; ++j) {
                    f16x8 v = *(f16x8*)&cw[lrow * 66 + lcol + j * 8];
                    *(f16x8*)&Fb[(size_t)grow * cs + cb + lcol + j * 8] = v;
                }
            }
        } else {
            // fp32 residual tile (L2 only): scalar path
            int cs = S - b2;
            #pragma unroll
            for (int nt = 0; nt < 4; ++nt) {
                int col = bn - b2 + nt * 16 + m16;
                float bv = bias[bn + nt * 16 + m16];
                #pragma unroll
                for (int mt = 0; mt < 2; ++mt)
                    #pragma unroll
                    for (int r = 0; r < 4; ++r) {
                        int row = rbase + mt * 16 + quad * 4 + r;
                        if (row < M) F2[(size_t)row * cs + col] = acc[mt][nt][r] + bv;
                    }
            }
        }
    }
}

// ---------- CSR build ----------
__global__ void zero_u32(unsigned int* __restrict__ p, int n) {
    int i = blockIdx.x * blockDim.x + threadIdx.x;
    if (i < n) p[i] = 0u;
}

__global__ void hist_dst(const int* __restrict__ dst, unsigned int* __restrict__ deg, int E) {
    int e = blockIdx.x * blockDim.x + threadIdx.x;
    if (e < E) atomicAdd(&deg[dst[e]], 1u);
}

__global__ void scan_deg(const unsigned int* __restrict__ deg,
                         unsigned int* __restrict__ row_ptr,
                         unsigned int* __restrict__ cursor, int n) {
    __shared__ unsigned int sums[1024];
    const int t = threadIdx.x;
    const int chunk = (n + 1023) / 1024;
    const int start = t * chunk;
    const int end = min(start + chunk, n);
    unsigned int s = 0;
    for (int i = start; i < end; ++i) s += deg[i];
    sums[t] = s;
    __syncthreads();
    for (int off = 1; off < 1024; off <<= 1) {
        unsigned int v = (t >= off) ? sums[t - off] : 0u;
        __syncthreads();
        sums[t] += v;
        __syncthreads();
    }
    unsigned int prefix = (t == 0) ? 0u : sums[t - 1];
    for (int i = start; i < end; ++i) {
        row_ptr[i] = prefix;
        cursor[i] = prefix;
        prefix += deg[i];
    }
    if (t == 1023) row_ptr[n] = sums[1023];
}

__global__ void scatter_edges(const int* __restrict__ src, const int* __restrict__ dst,
                              unsigned int* __restrict__ cursor,
                              int* __restrict__ csr_src, int E) {
    int e = blockIdx.x * blockDim.x + threadIdx.x;
    if (e < E) {
        unsigned int pos = atomicAdd(&cursor[dst[e]], 1u);
        csr_src[pos] = src[e];
    }
}

// ---------- fused GATv2 aggregate: 2 nodes per wave, 8 f16 dims per lane ----------
// Logit dot in packed f16 (v_pk_add_f16 + |x| via and-mask + v_dot2_f32_f16).
// Plain exp-sum (logits bounded). Scalar per-position clamped index prefetch.
// OUT_MODE: 0 = fp32 out + f16 A; 1 = f16 A only; 2 = head-mean -> out[N,32].
template <int HD, int D, bool HAS_RES, bool DO_ELU, int OUT_MODE>
__global__ __launch_bounds__(256) void gat_node_aggregate(
        const f16* __restrict__ fsb, const f16* __restrict__ fdb,
        const float* __restrict__ attn,
        const unsigned int* __restrict__ row_ptr,
        const int* __restrict__ csr_src,
        const float* __restrict__ resid, int RS,
        float* __restrict__ outF, f16* __restrict__ outA) {
    constexpr int LANES = HD / 8;   // active lanes per node (32 or 24)
    constexpr int GSZ = D / 8;      // lanes per head group (8 or 4)
    __shared__ float red[(OUT_MODE == 2) ? 8 : 1][(OUT_MODE == 2) ? HD : 1];

    const int wave = threadIdx.x >> 6;
    const int lane = threadIdx.x & 63;
    const int half = lane >> 5;            // 0 = node A, 1 = node B
    const int ln = lane & 31;              // lane within node
    const int t = blockIdx.x * 8 + wave * 2 + half;
    const bool active = (ln < LANES);
    const unsigned off = active ? 8u * ln : 0u;   // inactive lanes alias dims 0-7

    f16x2 fdp[4], a6p[4], a4p[4];
    if (active) {
        f16x8 dv = *(const f16x8*)&fdb[(unsigned)t * HD + off];
        float4 aA = *(const float4*)&attn[off];
        float4 aB = *(const float4*)&attn[off + 4];
        float av[8] = {aA.x, aA.y, aA.z, aA.w, aB.x, aB.y, aB.z, aB.w};
        #pragma unroll
        for (int i = 0; i < 4; ++i) {
            fdp[i] = (f16x2){dv[2 * i], dv[2 * i + 1]};
            a6p[i] = (f16x2){(f16)(0.6f * av[2 * i]), (f16)(0.6f * av[2 * i + 1])};
            a4p[i] = (f16x2){(f16)(0.4f * av[2 * i]), (f16)(0.4f * av[2 * i + 1])};
        }
    } else {
        #pragma unroll
        for (int i = 0; i < 4; ++i) {
            fdp[i] = (f16x2){0, 0};
            a6p[i] = (f16x2){0, 0};
            a4p[i] = (f16x2){0, 0};
        }
    }

    const int jj0 = (int)row_ptr[t];
    const int jj1 = (int)row_ptr[t + 1];
    const int deg = jj1 - jj0;
    const int last = jj1 - 1;
    const int degO = __shfl_xor(deg, 32, 64);
    const int mdeg = max(deg, degO);       // wave-uniform loop bound

    float acc[8];
    #pragma unroll
    for (int d = 0; d < 8; ++d) acc[d] = 0.f;
    float lh = 0.f;

    // prologue: features for edges 0..7, indices for refill edges 8..15 (all clamped)
    f16x8 buf[8];
    int cidx[8];
    #pragma unroll
    for (int u = 0; u < 8; ++u) {
        int e0 = min(jj0 + u, last);
        buf[u] = *(const f16x8*)&fsb[(unsigned)csr_src[e0] * HD + off];
        cidx[u] = csr_src[min(jj0 + 8 + u, last)];
    }

    for (int b = 0; b < mdeg; b += 8) {
        // indices for NEXT batch's refills (edges b+16..b+23), clamped per position
        int nidx[8];
        #pragma unroll
        for (int u = 0; u < 8; ++u)
            nidx[u] = csr_src[min(jj0 + b + 16 + u, last)];
        #pragma unroll
        for (int u = 0; u < 8; ++u) {
            const f16x8 cur = buf[u];
            buf[u] = *(const f16x8*)&fsb[(unsigned)cidx[u] * HD + off];  // edge b+8+u
            // packed-f16 logit dot: p = sum x*(0.6a) + |x|*(0.4a), f32 accumulate
            float p = 0.f;
            #pragma unroll
            for (int i = 0; i < 4; ++i) {
                f16x2 cp = (f16x2){cur[2 * i], cur[2 * i + 1]};
                f16x2 xp = cp + fdp[i];                       // v_pk_add_f16
                unsigned xu = __builtin_bit_cast(unsigned, xp) & 0x7FFF7FFFu;
                f16x2 xa = __builtin_bit_cast(f16x2, xu);     // packed |x|
                p = __builtin_amdgcn_fdot2(xp, a6p[i], p, false);
                p = __builtin_amdgcn_fdot2(xa, a4p[i], p, false);
            }
            #pragma unroll
            for (int o = 1; o < GSZ; o <<= 1)
                p += __shfl_xor(p, o, 64);
            float w = (b + u < deg) ? __expf(p) : 0.f;
            lh += w;
            #pragma unroll
            for (int d = 0; d < 8; ++d) acc[d] += w * (float)cur[d];   // fma_mix
        }
        #pragma unroll
        for (int u = 0; u < 8; ++u) cidx[u] = nidx[u];
    }

    float inv = (lh > 0.f) ? 1.f / lh : 0.f;
    float vout[8];
    #pragma unroll
    for (int d = 0; d < 8; ++d) vout[d] = acc[d] * inv;
    if (HAS_RES && active) {
        float4 rA = *(const float4*)&resid[(unsigned)t * RS + off];
        float4 rB = *(const float4*)&resid[(unsigned)t * RS + off + 4];
        vout[0] += rA.x; vout[1] += rA.y; vout[2] += rA.z; vout[3] += rA.w;
        vout[4] += rB.x; vout[5] += rB.y; vout[6] += rB.z; vout[7] += rB.w;
    }
    if (DO_ELU) {
        #pragma unroll
        for (int d = 0; d < 8; ++d) vout[d] = vout[d] > 0.f ? vout[d] : expm1f(vout[d]);
    }

    if (OUT_MODE == 2) {
        const int nib = wave * 2 + half;
        if (active) {
            *(float4*)&red[nib][off] = make_float4(vout[0], vout[1], vout[2], vout[3]);
            *(float4*)&red[nib][off + 4] = make_float4(vout[4], vout[5], vout[6], vout[7]);
        }
        __syncthreads();
        // 8 nodes x 32 cols = 256 threads
        int node = threadIdx.x >> 5;
        int col = threadIdx.x & 31;
        float ssum = 0.f;
        #pragma unroll
        for (int h = 0; h < 6; ++h) ssum += red[node][h * 32 + col];
        outF[(unsigned)(blockIdx.x * 8 + node) * 32 + col] = ssum * (1.f / 6.f);
    } else if (active) {
        f16x8 av;
        #pragma unroll
        for (int d = 0; d < 8; ++d) av[d] = (f16)vout[d];
        *(f16x8*)&outA[(unsigned)t * HD + off] = av;
        if (OUT_MODE == 0) {
            *(float4*)&outF[(unsigned)t * HD + off] = make_float4(vout[0], vout[1], vout[2], vout[3]);
            *(float4*)&outF[(unsigned)t * HD + off + 4] = make_float4(vout[4], vout[5], vout[6], vout[7]);
        }
    }
}

extern "C" void kernel_launch(void* const* d_in, const int* in_sizes, int n_in,
                              void* d_out, int out_size, void* d_ws, size_t ws_size,
                              hipStream_t stream) {
    const float* x   = (const float*)d_in[0];
    const int*   src = (const int*)d_in[1];
    const int*   dst = (const int*)d_in[2];
    const float* W0s = (const float*)d_in[3];
    const float* b0s = (const float*)d_in[4];
    const float* W0d = (const float*)d_in[5];
    const float* b0d = (const float*)d_in[6];
    const float* a0  = (const float*)d_in[7];
    const float* W1s = (const float*)d_in[8];
    const float* b1s = (const float*)d_in[9];
    const float* W1d = (const float*)d_in[10];
    const float* b1d = (const float*)d_in[11];
    const float* a1  = (const float*)d_in[12];
    const float* W2s = (const float*)d_in[13];
    const float* b2s = (const float*)d_in[14];
    const float* W2d = (const float*)d_in[15];
    const float* b2d = (const float*)d_in[16];
    const float* a2  = (const float*)d_in[17];
    const float* Wr2 = (const float*)d_in[18];
    const float* br2 = (const float*)d_in[19];

    // ---- workspace layout ----
    f16* FsH = (f16*)d_ws;                           // N*256 f16 (fs, dense gather target)
    f16* FdH = FsH + (size_t)NN * 256;               // N*256 f16 (fd)
    f16* A   = FdH + (size_t)NN * 256;               // N*256 f16 (GEMM A input)
    float* O0 = (float*)(A + (size_t)NN * 256);      // N*256 fp32 (L1 residual; later L2 Fr N*192)
    f16* Wt0 = (f16*)(O0 + (size_t)NN * 256);        // 512*128
    f16* Wt1 = Wt0 + 512 * 128;                      // 512*256
    f16* Wt2 = Wt1 + 512 * 256;                      // 576*256
    float* bias0 = (float*)(Wt2 + 576 * 256);        // 512
    float* bias1 = bias0 + 512;                      // 512
    float* bias2 = bias1 + 512;                      // 576
    unsigned int* row_ptr = (unsigned int*)(bias2 + 576);  // N+1
    unsigned int* cursor  = row_ptr + (NN + 1);
    unsigned int* deg     = cursor + NN;
    int* csr_src          = (int*)(deg + NN);        // E

    // ---- build CSR ----
    zero_u32<<<(NN + 255) / 256, 256, 0, stream>>>(deg, NN);
    hist_dst<<<(EE + 255) / 256, 256, 0, stream>>>(dst, deg, EE);
    scan_deg<<<1, 1024, 0, stream>>>(deg, row_ptr, cursor, NN);
    scatter_edges<<<(EE + 255) / 256, 256, 0, stream>>>(src, dst, cursor, csr_src, EE);

    // ---- all weight prep + x -> f16 in ONE launch ----
    {
        int total = SEG0 + SEG1 + SEG2 + SEG3;
        prep_all<<<(total + 255) / 256, 256, 0, stream>>>(
            W0s, b0s, W0d, b0d, W1s, b1s, W1d, b1d, W2s, b2s, W2d, b2d, Wr2, br2, x,
            Wt0, bias0, Wt1, bias1, Wt2, bias2, A);
    }

    const int gy = (NN + 255) / 256;           // 79 bm super-tiles (BM=256)
    const int gy8 = ((gy + 7) / 8) * 8;        // 80 (rounded for swizzle)
    const int nagg = NN / 8;                   // 2500 blocks, 8 nodes each (2 per wave)

    // ---- layer 0: A(x f16)[N,128] -> FsH/FdH[N,256] -> O0 fp32 + A f16 ----
    gemm_mfma_f16<<<gy8 * 8, 256, 0, stream>>>(A, Wt0, bias0,
                                               FsH, FdH, nullptr, 256, 512, NN, 128, 512, 8, gy);
    gat_node_aggregate<256, 64, false, true, 0><<<nagg, 256, 0, stream>>>(
        FsH, FdH, a0, row_ptr, csr_src, nullptr, 0, O0, A);

    // ---- layer 1: A -> FsH/FdH[N,256] -> A (identity residual O0 fp32) ----
    gemm_mfma_f16<<<gy8 * 8, 256, 0, stream>>>(A, Wt1, bias1,
                                               FsH, FdH, nullptr, 256, 512, NN, 256, 512, 8, gy);
    gat_node_aggregate<256, 64, true, true, 1><<<nagg, 256, 0, stream>>>(
        FsH, FdH, a1, row_ptr, csr_src, O0, 256, nullptr, A);

    // ---- layer 2: A -> FsH/FdH[N,192] + Fr(=O0 fp32)[N,192] -> d_out[N,32] ----
    gemm_mfma_f16<<<gy8 * 9, 256, 0, stream>>>(A, Wt2, bias2,
                                               FsH, FdH, O0, 192, 384, NN, 256, 576, 9, gy);
    gat_node_aggregate<192, 32, true, false, 2><<<nagg, 256, 0, stream>>>(
        FsH, FdH, a2, row_ptr, csr_src, O0, 192, (float*)d_out, nullptr);
}

// Round 18
// 329.931 us; speedup vs baseline: 1.3725x; 1.0021x over previous
//
#include <hip/hip_runtime.h>
#include <hip/hip_bf16.h>
#include <float.h>
#include <math.h>

// Problem constants (from reference)
#define NN 20000
#define EE 320000
#define IN_DIM 128
#define SLOPE_ 0.2f

typedef __attribute__((ext_vector_type(4))) float f32x4;
typedef _Float16 f16;
typedef __attribute__((ext_vector_type(2))) _Float16 f16x2;
typedef __attribute__((ext_vector_type(4))) _Float16 f16x4;
typedef __attribute__((ext_vector_type(8))) _Float16 f16x8;
typedef unsigned short ushort;

// ---------- weight prep element: concat + transpose, single f16 ----------
__device__ inline void prep_elem(const float* __restrict__ Wa, const float* __restrict__ ba, int na,
                                 const float* __restrict__ Wb, const float* __restrict__ bb, int nb,
                                 const float* __restrict__ Wc, const float* __restrict__ bc, int nc,
                                 int K, f16* __restrict__ Wt, float* __restrict__ bias_cat, int idx) {
    int n = idx / K;
    int k = idx - n * K;
    const float* W; const float* b; int nl; int ncols;
    if (n < na) { W = Wa; b = ba; nl = n; ncols = na; }
    else if (n < na + nb) { W = Wb; b = bb; nl = n - na; ncols = nb; }
    else { W = Wc; b = bc; nl = n - na - nb; ncols = nc; }
    Wt[(size_t)n * K + k] = (f16)W[(size_t)k * ncols + nl];
    if (k == 0) bias_cat[n] = b[nl];
}

// ---------- one launch: all 3 weight preps + x -> f16 + deg zero ----------
#define SEG0 (512 * 128)
#define SEG1 (512 * 256)
#define SEG2 (576 * 256)
#define SEG3 (NN * IN_DIM / 4)
#define SEG4 (NN)
__global__ void prep_all(const float* __restrict__ W0s, const float* __restrict__ b0s,
                         const float* __restrict__ W0d, const float* __restrict__ b0d,
                         const float* __restrict__ W1s, const float* __restrict__ b1s,
                         const float* __restrict__ W1d, const float* __restrict__ b1d,
                         const float* __restrict__ W2s, const float* __restrict__ b2s,
                         const float* __restrict__ W2d, const float* __restrict__ b2d,
                         const float* __restrict__ Wr2, const float* __restrict__ br2,
                         const float* __restrict__ x,
                         f16* __restrict__ Wt0, float* __restrict__ bias0,
                         f16* __restrict__ Wt1, float* __restrict__ bias1,
                         f16* __restrict__ Wt2, float* __restrict__ bias2,
                         f16* __restrict__ A, unsigned int* __restrict__ deg) {
    int idx = blockIdx.x * 256 + threadIdx.x;
    if (idx < SEG0) {
        prep_elem(W0s, b0s, 256, W0d, b0d, 256, nullptr, nullptr, 0, 128, Wt0, bias0, idx);
    } else if ((idx -= SEG0) < SEG1) {
        prep_elem(W1s, b1s, 256, W1d, b1d, 256, nullptr, nullptr, 0, 256, Wt1, bias1, idx);
    } else if ((idx -= SEG1) < SEG2) {
        prep_elem(W2s, b2s, 192, W2d, b2d, 192, Wr2, br2, 192, 256, Wt2, bias2, idx);
    } else if ((idx -= SEG2) < SEG3) {
        float4 v = ((const float4*)x)[idx];
        f16x4 o = {(f16)v.x, (f16)v.y, (f16)v.z, (f16)v.w};
        ((f16x4*)A)[idx] = o;
    } else if ((idx -= SEG3) < SEG4) {
        deg[idx] = 0u;
    }
}

// ---------- single-f16 MFMA GEMM v2: B-slice resident in LDS, ONE barrier total ----------
__global__ __launch_bounds__(256) void gemm_mfma_f16(
        const f16* __restrict__ A, const f16* __restrict__ Wt,
        const float* __restrict__ bias,
        f16* __restrict__ F0, f16* __restrict__ F1, float* __restrict__ F2,
        int b1, int b2, int M, int K, int S, int gx, int gy) {
    __shared__ f16 Bs[64 * 256];     // up to 32 KB, swizzled fragment order
    __shared__ f16 Cs[4][32 * 66];   // per-wave C staging, row stride 66

    const int bid = blockIdx.x;
    const int p = bid & 7;          // XCD slot
    const int q = bid >> 3;
    const int bn_i = q % gx;
    const int bm_i = (q / gx) * 8 + p;
    if (bm_i >= gy) return;
    const int bm = bm_i * 256;
    const int bn = bn_i * 64;

    const int tid = threadIdx.x;
    const int wave = tid >> 6;
    const int lane = tid & 63;
    const int m16 = lane & 15;
    const int quad = lane >> 4;

    // ---- stage whole B slice to LDS in fragment order ----
    {
        const int n = tid >> 2;      // 0..63 output col within tile
        const int q0 = tid & 3;      // quad of the 32-k chunk
        for (int j = 0; j * 32 < K; ++j) {
            int k0 = j * 32 + q0 * 8;
            f16x8 v = *(const f16x8*)(Wt + (size_t)(bn + n) * K + k0);
            int chunk = (j * 4 + (n >> 4)) * 64 + q0 * 16 + (n & 15);
            *(f16x8*)&Bs[chunk * 8] = v;
        }
    }
    __syncthreads();   // the ONLY barrier

    #pragma unroll
    for (int miter = 0; miter < 2; ++miter) {
        const int rbase = bm + wave * 64 + miter * 32;
        f32x4 acc[2][4];
        #pragma unroll
        for (int i = 0; i < 2; ++i)
            #pragma unroll
            for (int j = 0; j < 4; ++j) acc[i][j] = (f32x4){0.f, 0.f, 0.f, 0.f};

        int ar[2];
        #pragma unroll
        for (int mt = 0; mt < 2; ++mt) {
            int row = rbase + mt * 16 + m16;
            ar[mt] = row < M ? row : M - 1;
        }

        #pragma unroll 4
        for (int k0 = 0; k0 < K; k0 += 32) {
            f16x8 ah[2];
            #pragma unroll
            for (int mt = 0; mt < 2; ++mt)
                ah[mt] = *(const f16x8*)(A + (size_t)ar[mt] * K + k0 + quad * 8);
            #pragma unroll
            for (int nt = 0; nt < 4; ++nt) {
                f16x8 bs = *(const f16x8*)&Bs[(((k0 >> 5) * 4 + nt) * 64 + lane) * 8];
                #pragma unroll
                for (int mt = 0; mt < 2; ++mt)
                    acc[mt][nt] = __builtin_amdgcn_mfma_f32_16x16x32_f16(ah[mt], bs, acc[mt][nt], 0, 0, 0);
            }
        }

        // ---- epilogue for this miter ----
        if (bn < b2) {
            f16* __restrict__ Fb;
            int cs, cb;
            if (bn >= b1) { Fb = F1; cb = bn - b1; cs = b2 - b1; }
            else          { Fb = F0; cb = bn;      cs = b1; }
            f16* cw = &Cs[wave][0];
            #pragma unroll
            for (int nt = 0; nt < 4; ++nt) {
                float bv = bias[bn + nt * 16 + m16];
                #pragma unroll
                for (int mt = 0; mt < 2; ++mt)
                    #pragma unroll
                    for (int r = 0; r < 4; ++r) {
                        int row = mt * 16 + quad * 4 + r;   // 0..31 within miter
                        cw[row * 66 + nt * 16 + m16] = (f16)(acc[mt][nt][r] + bv);
                    }
            }
            int lrow = lane >> 1;
            int lcol = (lane & 1) * 32;
            int grow = rbase + lrow;
            if (grow < M) {
                #pragma unroll
                for (int j = 0; j < 4; ++j) {
                    f16x8 v = *(f16x8*)&cw[lrow * 66 + lcol + j * 8];
                    *(f16x8*)&Fb[(size_t)grow * cs + cb + lcol + j * 8] = v;
                }
            }
        } else {
            int cs = S - b2;
            #pragma unroll
            for (int nt = 0; nt < 4; ++nt) {
                int col = bn - b2 + nt * 16 + m16;
                float bv = bias[bn + nt * 16 + m16];
                #pragma unroll
                for (int mt = 0; mt < 2; ++mt)
                    #pragma unroll
                    for (int r = 0; r < 4; ++r) {
                        int row = rbase + mt * 16 + quad * 4 + r;
                        if (row < M) F2[(size_t)row * cs + col] = acc[mt][nt][r] + bv;
                    }
            }
        }
    }
}

// ---------- CSR build ----------
__global__ void hist_dst(const int* __restrict__ dst, unsigned int* __restrict__ deg, int E) {
    int e = blockIdx.x * blockDim.x + threadIdx.x;
    if (e < E) atomicAdd(&deg[dst[e]], 1u);
}

__global__ void scan_deg(const unsigned int* __restrict__ deg,
                         unsigned int* __restrict__ row_ptr,
                         unsigned int* __restrict__ cursor, int n) {
    __shared__ unsigned int sums[1024];
    const int t = threadIdx.x;
    const int chunk = (n + 1023) / 1024;
    const int start = t * chunk;
    const int end = min(start + chunk, n);
    unsigned int s = 0;
    for (int i = start; i < end; ++i) s += deg[i];
    sums[t] = s;
    __syncthreads();
    for (int off = 1; off < 1024; off <<= 1) {
        unsigned int v = (t >= off) ? sums[t - off] : 0u;
        __syncthreads();
        sums[t] += v;
        __syncthreads();
    }
    unsigned int prefix = (t == 0) ? 0u : sums[t - 1];
    for (int i = start; i < end; ++i) {
        row_ptr[i] = prefix;
        cursor[i] = prefix;
        prefix += deg[i];
    }
    if (t == 1023) row_ptr[n] = sums[1023];
}

__global__ void scatter_edges(const int* __restrict__ src, const int* __restrict__ dst,
                              unsigned int* __restrict__ cursor,
                              int* __restrict__ csr_src, int E) {
    int e = blockIdx.x * blockDim.x + threadIdx.x;
    if (e < E) {
        unsigned int pos = atomicAdd(&cursor[dst[e]], 1u);
        csr_src[pos] = src[e];
    }
}

// ---------- degree-descending counting sort -> perm (single block) ----------
__global__ void build_perm(const unsigned int* __restrict__ deg, int* __restrict__ perm, int n) {
    __shared__ unsigned int bins[64];
    __shared__ unsigned int base[64];
    const int t = threadIdx.x;  // 1024
    if (t < 64) bins[t] = 0u;
    __syncthreads();
    for (int i = t; i < n; i += 1024) {
        int b = 63 - (int)min(deg[i], 63u);   // descending degree
        atomicAdd(&bins[b], 1u);
    }
    __syncthreads();
    if (t == 0) {
        unsigned int s = 0;
        for (int b = 0; b < 64; ++b) { base[b] = s; s += bins[b]; }
    }
    __syncthreads();
    if (t < 64) bins[t] = base[t];   // reuse as cursors
    __syncthreads();
    for (int i = t; i < n; i += 1024) {
        int b = 63 - (int)min(deg[i], 63u);
        unsigned int pos = atomicAdd(&bins[b], 1u);
        perm[pos] = i;
    }
}

// ---------- fused GATv2 aggregate: 2 nodes per wave (degree-paired), 8 f16 dims/lane ----------
// t = perm[...]: adjacent sorted nodes share a wave -> max(degA,degB) ~ avg (kills padding).
// OUT_MODE: 0 = fp32 out + f16 A; 1 = f16 A only; 2 = head-mean -> out[N,32].
template <int HD, int D, bool HAS_RES, bool DO_ELU, int OUT_MODE>
__global__ __launch_bounds__(256) void gat_node_aggregate(
        const f16* __restrict__ fsb, const f16* __restrict__ fdb,
        const float* __restrict__ attn,
        const unsigned int* __restrict__ row_ptr,
        const int* __restrict__ csr_src,
        const int* __restrict__ perm,
        const float* __restrict__ resid, int RS,
        float* __restrict__ outF, f16* __restrict__ outA) {
    constexpr int LANES = HD / 8;   // active lanes per node (32 or 24)
    constexpr int GSZ = D / 8;      // lanes per head group (8 or 4)
    __shared__ float red[(OUT_MODE == 2) ? 8 : 1][(OUT_MODE == 2) ? HD : 1];

    const int wave = threadIdx.x >> 6;
    const int lane = threadIdx.x & 63;
    const int half = lane >> 5;            // 0 = node A, 1 = node B
    const int ln = lane & 31;              // lane within node
    const int t = perm[blockIdx.x * 8 + wave * 2 + half];
    const bool active = (ln < LANES);
    const unsigned off = active ? 8u * ln : 0u;   // inactive lanes alias dims 0-7

    f16x2 fdp[4], a6p[4], a4p[4];
    if (active) {
        f16x8 dv = *(const f16x8*)&fdb[(unsigned)t * HD + off];
        float4 aA = *(const float4*)&attn[off];
        float4 aB = *(const float4*)&attn[off + 4];
        float av[8] = {aA.x, aA.y, aA.z, aA.w, aB.x, aB.y, aB.z, aB.w};
        #pragma unroll
        for (int i = 0; i < 4; ++i) {
            fdp[i] = (f16x2){dv[2 * i], dv[2 * i + 1]};
            a6p[i] = (f16x2){(f16)(0.6f * av[2 * i]), (f16)(0.6f * av[2 * i + 1])};
            a4p[i] = (f16x2){(f16)(0.4f * av[2 * i]), (f16)(0.4f * av[2 * i + 1])};
        }
    } else {
        #pragma unroll
        for (int i = 0; i < 4; ++i) {
            fdp[i] = (f16x2){0, 0};
            a6p[i] = (f16x2){0, 0};
            a4p[i] = (f16x2){0, 0};
        }
    }

    const int jj0 = (int)row_ptr[t];
    const int jj1 = (int)row_ptr[t + 1];
    const int deg = jj1 - jj0;
    const int last = jj1 - 1;
    const int degO = __shfl_xor(deg, 32, 64);
    const int mdeg = max(deg, degO);       // wave-uniform loop bound (now ~avg after pairing)

    float acc[8];
    #pragma unroll
    for (int d = 0; d < 8; ++d) acc[d] = 0.f;
    float lh = 0.f;

    // prologue: features for edges 0..7, indices for refill edges 8..15 (all clamped)
    f16x8 buf[8];
    int cidx[8];
    #pragma unroll
    for (int u = 0; u < 8; ++u) {
        int e0 = min(jj0 + u, last);
        buf[u] = *(const f16x8*)&fsb[(unsigned)csr_src[e0] * HD + off];
        cidx[u] = csr_src[min(jj0 + 8 + u, last)];
    }

    for (int b = 0; b < mdeg; b += 8) {
        int nidx[8];
        #pragma unroll
        for (int u = 0; u < 8; ++u)
            nidx[u] = csr_src[min(jj0 + b + 16 + u, last)];
        #pragma unroll
        for (int u = 0; u < 8; ++u) {
            const f16x8 cur = buf[u];
            buf[u] = *(const f16x8*)&fsb[(unsigned)cidx[u] * HD + off];  // edge b+8+u
            float p = 0.f;
            #pragma unroll
            for (int i = 0; i < 4; ++i) {
                f16x2 cp = (f16x2){cur[2 * i], cur[2 * i + 1]};
                f16x2 xp = cp + fdp[i];                       // v_pk_add_f16
                unsigned xu = __builtin_bit_cast(unsigned, xp) & 0x7FFF7FFFu;
                f16x2 xa = __builtin_bit_cast(f16x2, xu);     // packed |x|
                p = __builtin_amdgcn_fdot2(xp, a6p[i], p, false);
                p = __builtin_amdgcn_fdot2(xa, a4p[i], p, false);
            }
            #pragma unroll
            for (int o = 1; o < GSZ; o <<= 1)
                p += __shfl_xor(p, o, 64);
            float w = (b + u < deg) ? __expf(p) : 0.f;
            lh += w;
            #pragma unroll
            for (int d = 0; d < 8; ++d) acc[d] += w * (float)cur[d];   // fma_mix
        }
        #pragma unroll
        for (int u = 0; u < 8; ++u) cidx[u] = nidx[u];
    }

    float inv = (lh > 0.f) ? 1.f / lh : 0.f;
    float vout[8];
    #pragma unroll
    for (int d = 0; d < 8; ++d) vout[d] = acc[d] * inv;
    if (HAS_RES && active) {
        float4 rA = *(const float4*)&resid[(unsigned)t * RS + off];
        float4 rB = *(const float4*)&resid[(unsigned)t * RS + off + 4];
        vout[0] += rA.x; vout[1] += rA.y; vout[2] += rA.z; vout[3] += rA.w;
        vout[4] += rB.x; vout[5] += rB.y; vout[6] += rB.z; vout[7] += rB.w;
    }
    if (DO_ELU) {
        #pragma unroll
        for (int d = 0; d < 8; ++d) vout[d] = vout[d] > 0.f ? vout[d] : expm1f(vout[d]);
    }

    if (OUT_MODE == 2) {
        const int nib = wave * 2 + half;
        if (active) {
            *(float4*)&red[nib][off] = make_float4(vout[0], vout[1], vout[2], vout[3]);
            *(float4*)&red[nib][off + 4] = make_float4(vout[4], vout[5], vout[6], vout[7]);
        }
        __syncthreads();
        // 8 nodes x 32 cols = 256 threads
        int node = threadIdx.x >> 5;
        int col = threadIdx.x & 31;
        int tg = perm[blockIdx.x * 8 + node];
        float ssum = 0.f;
        #pragma unroll
        for (int h = 0; h < 6; ++h) ssum += red[node][h * 32 + col];
        outF[(unsigned)tg * 32 + col] = ssum * (1.f / 6.f);
    } else if (active) {
        f16x8 av;
        #pragma unroll
        for (int d = 0; d < 8; ++d) av[d] = (f16)vout[d];
        *(f16x8*)&outA[(unsigned)t * HD + off] = av;
        if (OUT_MODE == 0) {
            *(float4*)&outF[(unsigned)t * HD + off] = make_float4(vout[0], vout[1], vout[2], vout[3]);
            *(float4*)&outF[(unsigned)t * HD + off + 4] = make_float4(vout[4], vout[5], vout[6], vout[7]);
        }
    }
}

extern "C" void kernel_launch(void* const* d_in, const int* in_sizes, int n_in,
                              void* d_out, int out_size, void* d_ws, size_t ws_size,
                              hipStream_t stream) {
    const float* x   = (const float*)d_in[0];
    const int*   src = (const int*)d_in[1];
    const int*   dst = (const int*)d_in[2];
    const float* W0s = (const float*)d_in[3];
    const float* b0s = (const float*)d_in[4];
    const float* W0d = (const float*)d_in[5];
    const float* b0d = (const float*)d_in[6];
    const float* a0  = (const float*)d_in[7];
    const float* W1s = (const float*)d_in[8];
    const float* b1s = (const float*)d_in[9];
    const float* W1d = (const float*)d_in[10];
    const float* b1d = (const float*)d_in[11];
    const float* a1  = (const float*)d_in[12];
    const float* W2s = (const float*)d_in[13];
    const float* b2s = (const float*)d_in[14];
    const float* W2d = (const float*)d_in[15];
    const float* b2d = (const float*)d_in[16];
    const float* a2  = (const float*)d_in[17];
    const float* Wr2 = (const float*)d_in[18];
    const float* br2 = (const float*)d_in[19];

    // ---- workspace layout ----
    f16* FsH = (f16*)d_ws;                           // N*256 f16 (fs, dense gather target)
    f16* FdH = FsH + (size_t)NN * 256;               // N*256 f16 (fd)
    f16* A   = FdH + (size_t)NN * 256;               // N*256 f16 (GEMM A input)
    float* O0 = (float*)(A + (size_t)NN * 256);      // N*256 fp32 (L1 residual; later L2 Fr N*192)
    f16* Wt0 = (f16*)(O0 + (size_t)NN * 256);        // 512*128
    f16* Wt1 = Wt0 + 512 * 128;                      // 512*256
    f16* Wt2 = Wt1 + 512 * 256;                      // 576*256
    float* bias0 = (float*)(Wt2 + 576 * 256);        // 512
    float* bias1 = bias0 + 512;                      // 512
    float* bias2 = bias1 + 512;                      // 576
    unsigned int* row_ptr = (unsigned int*)(bias2 + 576);  // N+1
    unsigned int* cursor  = row_ptr + (NN + 1);
    unsigned int* deg     = cursor + NN;
    int* csr_src          = (int*)(deg + NN);        // E
    int* perm             = csr_src + EE;            // N

    // ---- prep (weights + x->f16 + deg zero) first, then CSR chain ----
    {
        int total = SEG0 + SEG1 + SEG2 + SEG3 + SEG4;
        prep_all<<<(total + 255) / 256, 256, 0, stream>>>(
            W0s, b0s, W0d, b0d, W1s, b1s, W1d, b1d, W2s, b2s, W2d, b2d, Wr2, br2, x,
            Wt0, bias0, Wt1, bias1, Wt2, bias2, A, deg);
    }
    hist_dst<<<(EE + 255) / 256, 256, 0, stream>>>(dst, deg, EE);
    scan_deg<<<1, 1024, 0, stream>>>(deg, row_ptr, cursor, NN);
    scatter_edges<<<(EE + 255) / 256, 256, 0, stream>>>(src, dst, cursor, csr_src, EE);
    build_perm<<<1, 1024, 0, stream>>>(deg, perm, NN);

    const int gy = (NN + 255) / 256;           // 79 bm super-tiles (BM=256)
    const int gy8 = ((gy + 7) / 8) * 8;        // 80 (rounded for swizzle)
    const int nagg = NN / 8;                   // 2500 blocks, 8 nodes each (2 per wave)

    // ---- layer 0: A(x f16)[N,128] -> FsH/FdH[N,256] -> O0 fp32 + A f16 ----
    gemm_mfma_f16<<<gy8 * 8, 256, 0, stream>>>(A, Wt0, bias0,
                                               FsH, FdH, nullptr, 256, 512, NN, 128, 512, 8, gy);
    gat_node_aggregate<256, 64, false, true, 0><<<nagg, 256, 0, stream>>>(
        FsH, FdH, a0, row_ptr, csr_src, perm, nullptr, 0, O0, A);

    // ---- layer 1: A -> FsH/FdH[N,256] -> A (identity residual O0 fp32) ----
    gemm_mfma_f16<<<gy8 * 8, 256, 0, stream>>>(A, Wt1, bias1,
                                               FsH, FdH, nullptr, 256, 512, NN, 256, 512, 8, gy);
    gat_node_aggregate<256, 64, true, true, 1><<<nagg, 256, 0, stream>>>(
        FsH, FdH, a1, row_ptr, csr_src, perm, O0, 256, nullptr, A);

    // ---- layer 2: A -> FsH/FdH[N,192] + Fr(=O0 fp32)[N,192] -> d_out[N,32] ----
    gemm_mfma_f16<<<gy8 * 9, 256, 0, stream>>>(A, Wt2, bias2,
                                               FsH, FdH, O0, 192, 384, NN, 256, 576, 9, gy);
    gat_node_aggregate<192, 32, true, false, 2><<<nagg, 256, 0, stream>>>(
        FsH, FdH, a2, row_ptr, csr_src, perm, O0, 192, (float*)d_out, nullptr);
}

// Round 19
// 323.643 us; speedup vs baseline: 1.3992x; 1.0194x over previous
//
#include <hip/hip_runtime.h>
#include <hip/hip_bf16.h>
#include <float.h>
#include <math.h>

// Problem constants (from reference)
#define NN 20000
#define EE 320000
#define IN_DIM 128
#define SLOPE_ 0.2f

typedef __attribute__((ext_vector_type(4))) float f32x4;
typedef _Float16 f16;
typedef __attribute__((ext_vector_type(2))) _Float16 f16x2;
typedef __attribute__((ext_vector_type(4))) _Float16 f16x4;
typedef __attribute__((ext_vector_type(8))) _Float16 f16x8;
typedef unsigned short ushort;

// ---------- weight prep element: concat + transpose, single f16 ----------
__device__ inline void prep_elem(const float* __restrict__ Wa, const float* __restrict__ ba, int na,
                                 const float* __restrict__ Wb, const float* __restrict__ bb, int nb,
                                 const float* __restrict__ Wc, const float* __restrict__ bc, int nc,
                                 int K, f16* __restrict__ Wt, float* __restrict__ bias_cat, int idx) {
    int n = idx / K;
    int k = idx - n * K;
    const float* W; const float* b; int nl; int ncols;
    if (n < na) { W = Wa; b = ba; nl = n; ncols = na; }
    else if (n < na + nb) { W = Wb; b = bb; nl = n - na; ncols = nb; }
    else { W = Wc; b = bc; nl = n - na - nb; ncols = nc; }
    Wt[(size_t)n * K + k] = (f16)W[(size_t)k * ncols + nl];
    if (k == 0) bias_cat[n] = b[nl];
}

// ---------- one launch: all 3 weight preps + x -> f16 + deg zero ----------
#define SEG0 (512 * 128)
#define SEG1 (512 * 256)
#define SEG2 (576 * 256)
#define SEG3 (NN * IN_DIM / 4)
#define SEG4 (NN)
__global__ void prep_all(const float* __restrict__ W0s, const float* __restrict__ b0s,
                         const float* __restrict__ W0d, const float* __restrict__ b0d,
                         const float* __restrict__ W1s, const float* __restrict__ b1s,
                         const float* __restrict__ W1d, const float* __restrict__ b1d,
                         const float* __restrict__ W2s, const float* __restrict__ b2s,
                         const float* __restrict__ W2d, const float* __restrict__ b2d,
                         const float* __restrict__ Wr2, const float* __restrict__ br2,
                         const float* __restrict__ x,
                         f16* __restrict__ Wt0, float* __restrict__ bias0,
                         f16* __restrict__ Wt1, float* __restrict__ bias1,
                         f16* __restrict__ Wt2, float* __restrict__ bias2,
                         f16* __restrict__ A, unsigned int* __restrict__ deg) {
    int idx = blockIdx.x * 256 + threadIdx.x;
    if (idx < SEG0) {
        prep_elem(W0s, b0s, 256, W0d, b0d, 256, nullptr, nullptr, 0, 128, Wt0, bias0, idx);
    } else if ((idx -= SEG0) < SEG1) {
        prep_elem(W1s, b1s, 256, W1d, b1d, 256, nullptr, nullptr, 0, 256, Wt1, bias1, idx);
    } else if ((idx -= SEG1) < SEG2) {
        prep_elem(W2s, b2s, 192, W2d, b2d, 192, Wr2, br2, 192, 256, Wt2, bias2, idx);
    } else if ((idx -= SEG2) < SEG3) {
        float4 v = ((const float4*)x)[idx];
        f16x4 o = {(f16)v.x, (f16)v.y, (f16)v.z, (f16)v.w};
        ((f16x4*)A)[idx] = o;
    } else if ((idx -= SEG3) < SEG4) {
        deg[idx] = 0u;
    }
}

// ---------- single-f16 MFMA GEMM v2: B-slice resident in LDS, ONE barrier total ----------
__global__ __launch_bounds__(256) void gemm_mfma_f16(
        const f16* __restrict__ A, const f16* __restrict__ Wt,
        const float* __restrict__ bias,
        f16* __restrict__ F0, f16* __restrict__ F1, float* __restrict__ F2,
        int b1, int b2, int M, int K, int S, int gx, int gy) {
    __shared__ f16 Bs[64 * 256];     // up to 32 KB, swizzled fragment order
    __shared__ f16 Cs[4][32 * 66];   // per-wave C staging, row stride 66

    const int bid = blockIdx.x;
    const int p = bid & 7;          // XCD slot
    const int q = bid >> 3;
    const int bn_i = q % gx;
    const int bm_i = (q / gx) * 8 + p;
    if (bm_i >= gy) return;
    const int bm = bm_i * 256;
    const int bn = bn_i * 64;

    const int tid = threadIdx.x;
    const int wave = tid >> 6;
    const int lane = tid & 63;
    const int m16 = lane & 15;
    const int quad = lane >> 4;

    // ---- stage whole B slice to LDS in fragment order ----
    {
        const int n = tid >> 2;      // 0..63 output col within tile
        const int q0 = tid & 3;      // quad of the 32-k chunk
        for (int j = 0; j * 32 < K; ++j) {
            int k0 = j * 32 + q0 * 8;
            f16x8 v = *(const f16x8*)(Wt + (size_t)(bn + n) * K + k0);
            int chunk = (j * 4 + (n >> 4)) * 64 + q0 * 16 + (n & 15);
            *(f16x8*)&Bs[chunk * 8] = v;
        }
    }
    __syncthreads();   // the ONLY barrier

    #pragma unroll
    for (int miter = 0; miter < 2; ++miter) {
        const int rbase = bm + wave * 64 + miter * 32;
        f32x4 acc[2][4];
        #pragma unroll
        for (int i = 0; i < 2; ++i)
            #pragma unroll
            for (int j = 0; j < 4; ++j) acc[i][j] = (f32x4){0.f, 0.f, 0.f, 0.f};

        int ar[2];
        #pragma unroll
        for (int mt = 0; mt < 2; ++mt) {
            int row = rbase + mt * 16 + m16;
            ar[mt] = row < M ? row : M - 1;
        }

        #pragma unroll 4
        for (int k0 = 0; k0 < K; k0 += 32) {
            f16x8 ah[2];
            #pragma unroll
            for (int mt = 0; mt < 2; ++mt)
                ah[mt] = *(const f16x8*)(A + (size_t)ar[mt] * K + k0 + quad * 8);
            #pragma unroll
            for (int nt = 0; nt < 4; ++nt) {
                f16x8 bs = *(const f16x8*)&Bs[(((k0 >> 5) * 4 + nt) * 64 + lane) * 8];
                #pragma unroll
                for (int mt = 0; mt < 2; ++mt)
                    acc[mt][nt] = __builtin_amdgcn_mfma_f32_16x16x32_f16(ah[mt], bs, acc[mt][nt], 0, 0, 0);
            }
        }

        // ---- epilogue for this miter ----
        if (bn < b2) {
            f16* __restrict__ Fb;
            int cs, cb;
            if (bn >= b1) { Fb = F1; cb = bn - b1; cs = b2 - b1; }
            else          { Fb = F0; cb = bn;      cs = b1; }
            f16* cw = &Cs[wave][0];
            #pragma unroll
            for (int nt = 0; nt < 4; ++nt) {
                float bv = bias[bn + nt * 16 + m16];
                #pragma unroll
                for (int mt = 0; mt < 2; ++mt)
                    #pragma unroll
                    for (int r = 0; r < 4; ++r) {
                        int row = mt * 16 + quad * 4 + r;   // 0..31 within miter
                        cw[row * 66 + nt * 16 + m16] = (f16)(acc[mt][nt][r] + bv);
                    }
            }
            int lrow = lane >> 1;
            int lcol = (lane & 1) * 32;
            int grow = rbase + lrow;
            if (grow < M) {
                #pragma unroll
                for (int j = 0; j < 4; ++j) {
                    f16x8 v = *(f16x8*)&cw[lrow * 66 + lcol + j * 8];
                    *(f16x8*)&Fb[(size_t)grow * cs + cb + lcol + j * 8] = v;
                }
            }
        } else {
            int cs = S - b2;
            #pragma unroll
            for (int nt = 0; nt < 4; ++nt) {
                int col = bn - b2 + nt * 16 + m16;
                float bv = bias[bn + nt * 16 + m16];
                #pragma unroll
                for (int mt = 0; mt < 2; ++mt)
                    #pragma unroll
                    for (int r = 0; r < 4; ++r) {
                        int row = rbase + mt * 16 + quad * 4 + r;
                        if (row < M) F2[(size_t)row * cs + col] = acc[mt][nt][r] + bv;
                    }
            }
        }
    }
}

// ---------- CSR build ----------
__global__ void hist_dst(const int* __restrict__ dst, unsigned int* __restrict__ deg, int E) {
    int e = blockIdx.x * blockDim.x + threadIdx.x;
    if (e < E) atomicAdd(&deg[dst[e]], 1u);
}

// scan + degree-descending counting-sort perm, fused (single block)
__global__ void scan_perm(const unsigned int* __restrict__ deg,
                          unsigned int* __restrict__ row_ptr,
                          unsigned int* __restrict__ cursor,
                          int* __restrict__ perm, int n) {
    __shared__ unsigned int sums[1024];
    __shared__ unsigned int bins[64];
    __shared__ unsigned int base[64];
    const int t = threadIdx.x;
    const int chunk = (n + 1023) / 1024;
    const int start = t * chunk;
    const int end = min(start + chunk, n);
    // --- exclusive scan for row_ptr/cursor + histogram for perm, one pass over deg ---
    if (t < 64) bins[t] = 0u;
    __syncthreads();
    unsigned int s = 0;
    for (int i = start; i < end; ++i) {
        unsigned int d = deg[i];
        s += d;
        atomicAdd(&bins[63 - (int)min(d, 63u)], 1u);
    }
    sums[t] = s;
    __syncthreads();
    for (int off = 1; off < 1024; off <<= 1) {
        unsigned int v = (t >= off) ? sums[t - off] : 0u;
        __syncthreads();
        sums[t] += v;
        __syncthreads();
    }
    unsigned int prefix = (t == 0) ? 0u : sums[t - 1];
    for (int i = start; i < end; ++i) {
        row_ptr[i] = prefix;
        cursor[i] = prefix;
        prefix += deg[i];
    }
    if (t == 1023) row_ptr[n] = sums[1023];
    // --- bin bases, then scatter perm ---
    if (t == 0) {
        unsigned int bs = 0;
        for (int b = 0; b < 64; ++b) { base[b] = bs; bs += bins[b]; }
    }
    __syncthreads();
    if (t < 64) bins[t] = base[t];   // reuse as cursors
    __syncthreads();
    for (int i = t; i < n; i += 1024) {
        int b = 63 - (int)min(deg[i], 63u);
        unsigned int pos = atomicAdd(&bins[b], 1u);
        perm[pos] = i;
    }
}

__global__ void scatter_edges(const int* __restrict__ src, const int* __restrict__ dst,
                              unsigned int* __restrict__ cursor,
                              int* __restrict__ csr_src, int E) {
    int e = blockIdx.x * blockDim.x + threadIdx.x;
    if (e < E) {
        unsigned int pos = atomicAdd(&cursor[dst[e]], 1u);
        csr_src[pos] = src[e];
    }
}

// ---------- fused GATv2 aggregate: 2 nodes per wave (degree-paired), 8 f16 dims/lane ----------
// In-place index refill (cidx[u] reloaded right after use -> no nidx staging, -8 VGPR).
// OUT_MODE: 0 = fp32 out + f16 A; 1 = f16 A only; 2 = head-mean -> out[N,32].
template <int HD, int D, bool HAS_RES, bool DO_ELU, int OUT_MODE>
__global__ __launch_bounds__(256) void gat_node_aggregate(
        const f16* __restrict__ fsb, const f16* __restrict__ fdb,
        const float* __restrict__ attn,
        const unsigned int* __restrict__ row_ptr,
        const int* __restrict__ csr_src,
        const int* __restrict__ perm,
        const float* __restrict__ resid, int RS,
        float* __restrict__ outF, f16* __restrict__ outA) {
    constexpr int LANES = HD / 8;   // active lanes per node (32 or 24)
    constexpr int GSZ = D / 8;      // lanes per head group (8 or 4)
    __shared__ float red[(OUT_MODE == 2) ? 8 : 1][(OUT_MODE == 2) ? HD : 1];

    const int wave = threadIdx.x >> 6;
    const int lane = threadIdx.x & 63;
    const int half = lane >> 5;            // 0 = node A, 1 = node B
    const int ln = lane & 31;              // lane within node
    const int t = perm[blockIdx.x * 8 + wave * 2 + half];
    const bool active = (ln < LANES);
    const unsigned off = active ? 8u * ln : 0u;   // inactive lanes alias dims 0-7

    f16x2 fdp[4], a6p[4], a4p[4];
    if (active) {
        f16x8 dv = *(const f16x8*)&fdb[(unsigned)t * HD + off];
        float4 aA = *(const float4*)&attn[off];
        float4 aB = *(const float4*)&attn[off + 4];
        float av[8] = {aA.x, aA.y, aA.z, aA.w, aB.x, aB.y, aB.z, aB.w};
        #pragma unroll
        for (int i = 0; i < 4; ++i) {
            fdp[i] = (f16x2){dv[2 * i], dv[2 * i + 1]};
            a6p[i] = (f16x2){(f16)(0.6f * av[2 * i]), (f16)(0.6f * av[2 * i + 1])};
            a4p[i] = (f16x2){(f16)(0.4f * av[2 * i]), (f16)(0.4f * av[2 * i + 1])};
        }
    } else {
        #pragma unroll
        for (int i = 0; i < 4; ++i) {
            fdp[i] = (f16x2){0, 0};
            a6p[i] = (f16x2){0, 0};
            a4p[i] = (f16x2){0, 0};
        }
    }

    const int jj0 = (int)row_ptr[t];
    const int jj1 = (int)row_ptr[t + 1];
    const int deg = jj1 - jj0;
    const int last = jj1 - 1;
    const int degO = __shfl_xor(deg, 32, 64);
    const int mdeg = max(deg, degO);       // wave-uniform loop bound

    float acc[8];
    #pragma unroll
    for (int d = 0; d < 8; ++d) acc[d] = 0.f;
    float lh = 0.f;

    // prologue: features for edges 0..7, indices for refill edges 8..15 (all clamped)
    f16x8 buf[8];
    int cidx[8];
    #pragma unroll
    for (int u = 0; u < 8; ++u) {
        int e0 = min(jj0 + u, last);
        buf[u] = *(const f16x8*)&fsb[(unsigned)csr_src[e0] * HD + off];
        cidx[u] = csr_src[min(jj0 + 8 + u, last)];
    }

    for (int b = 0; b < mdeg; b += 8) {
        #pragma unroll
        for (int u = 0; u < 8; ++u) {
            const f16x8 cur = buf[u];
            buf[u] = *(const f16x8*)&fsb[(unsigned)cidx[u] * HD + off];  // edge b+8+u
            cidx[u] = csr_src[min(jj0 + b + 16 + u, last)];             // edge b+16+u (in place)
            float p = 0.f;
            #pragma unroll
            for (int i = 0; i < 4; ++i) {
                f16x2 cp = (f16x2){cur[2 * i], cur[2 * i + 1]};
                f16x2 xp = cp + fdp[i];                       // v_pk_add_f16
                unsigned xu = __builtin_bit_cast(unsigned, xp) & 0x7FFF7FFFu;
                f16x2 xa = __builtin_bit_cast(f16x2, xu);     // packed |x|
                p = __builtin_amdgcn_fdot2(xp, a6p[i], p, false);
                p = __builtin_amdgcn_fdot2(xa, a4p[i], p, false);
            }
            #pragma unroll
            for (int o = 1; o < GSZ; o <<= 1)
                p += __shfl_xor(p, o, 64);
            float w = (b + u < deg) ? __expf(p) : 0.f;
            lh += w;
            #pragma unroll
            for (int d = 0; d < 8; ++d) acc[d] += w * (float)cur[d];   // fma_mix
        }
    }

    float inv = (lh > 0.f) ? 1.f / lh : 0.f;
    float vout[8];
    #pragma unroll
    for (int d = 0; d < 8; ++d) vout[d] = acc[d] * inv;
    if (HAS_RES && active) {
        float4 rA = *(const float4*)&resid[(unsigned)t * RS + off];
        float4 rB = *(const float4*)&resid[(unsigned)t * RS + off + 4];
        vout[0] += rA.x; vout[1] += rA.y; vout[2] += rA.z; vout[3] += rA.w;
        vout[4] += rB.x; vout[5] += rB.y; vout[6] += rB.z; vout[7] += rB.w;
    }
    if (DO_ELU) {
        #pragma unroll
        for (int d = 0; d < 8; ++d) vout[d] = vout[d] > 0.f ? vout[d] : expm1f(vout[d]);
    }

    if (OUT_MODE == 2) {
        const int nib = wave * 2 + half;
        if (active) {
            *(float4*)&red[nib][off] = make_float4(vout[0], vout[1], vout[2], vout[3]);
            *(float4*)&red[nib][off + 4] = make_float4(vout[4], vout[5], vout[6], vout[7]);
        }
        __syncthreads();
        // 8 nodes x 32 cols = 256 threads
        int node = threadIdx.x >> 5;
        int col = threadIdx.x & 31;
        int tg = perm[blockIdx.x * 8 + node];
        float ssum = 0.f;
        #pragma unroll
        for (int h = 0; h < 6; ++h) ssum += red[node][h * 32 + col];
        outF[(unsigned)tg * 32 + col] = ssum * (1.f / 6.f);
    } else if (active) {
        f16x8 av;
        #pragma unroll
        for (int d = 0; d < 8; ++d) av[d] = (f16)vout[d];
        *(f16x8*)&outA[(unsigned)t * HD + off] = av;
        if (OUT_MODE == 0) {
            *(float4*)&outF[(unsigned)t * HD + off] = make_float4(vout[0], vout[1], vout[2], vout[3]);
            *(float4*)&outF[(unsigned)t * HD + off + 4] = make_float4(vout[4], vout[5], vout[6], vout[7]);
        }
    }
}

extern "C" void kernel_launch(void* const* d_in, const int* in_sizes, int n_in,
                              void* d_out, int out_size, void* d_ws, size_t ws_size,
                              hipStream_t stream) {
    const float* x   = (const float*)d_in[0];
    const int*   src = (const int*)d_in[1];
    const int*   dst = (const int*)d_in[2];
    const float* W0s = (const float*)d_in[3];
    const float* b0s = (const float*)d_in[4];
    const float* W0d = (const float*)d_in[5];
    const float* b0d = (const float*)d_in[6];
    const float* a0  = (const float*)d_in[7];
    const float* W1s = (const float*)d_in[8];
    const float* b1s = (const float*)d_in[9];
    const float* W1d = (const float*)d_in[10];
    const float* b1d = (const float*)d_in[11];
    const float* a1  = (const float*)d_in[12];
    const float* W2s = (const float*)d_in[13];
    const float* b2s = (const float*)d_in[14];
    const float* W2d = (const float*)d_in[15];
    const float* b2d = (const float*)d_in[16];
    const float* a2  = (const float*)d_in[17];
    const float* Wr2 = (const float*)d_in[18];
    const float* br2 = (const float*)d_in[19];

    // ---- workspace layout ----
    f16* FsH = (f16*)d_ws;                           // N*256 f16 (fs, dense gather target)
    f16* FdH = FsH + (size_t)NN * 256;               // N*256 f16 (fd)
    f16* A   = FdH + (size_t)NN * 256;               // N*256 f16 (GEMM A input)
    float* O0 = (float*)(A + (size_t)NN * 256);      // N*256 fp32 (L1 residual; later L2 Fr N*192)
    f16* Wt0 = (f16*)(O0 + (size_t)NN * 256);        // 512*128
    f16* Wt1 = Wt0 + 512 * 128;                      // 512*256
    f16* Wt2 = Wt1 + 512 * 256;                      // 576*256
    float* bias0 = (float*)(Wt2 + 576 * 256);        // 512
    float* bias1 = bias0 + 512;                      // 512
    float* bias2 = bias1 + 512;                      // 576
    unsigned int* row_ptr = (unsigned int*)(bias2 + 576);  // N+1
    unsigned int* cursor  = row_ptr + (NN + 1);
    unsigned int* deg     = cursor + NN;
    int* csr_src          = (int*)(deg + NN);        // E
    int* perm             = csr_src + EE;            // N

    // ---- prep (weights + x->f16 + deg zero) first, then CSR chain ----
    {
        int total = SEG0 + SEG1 + SEG2 + SEG3 + SEG4;
        prep_all<<<(total + 255) / 256, 256, 0, stream>>>(
            W0s, b0s, W0d, b0d, W1s, b1s, W1d, b1d, W2s, b2s, W2d, b2d, Wr2, br2, x,
            Wt0, bias0, Wt1, bias1, Wt2, bias2, A, deg);
    }
    hist_dst<<<(EE + 255) / 256, 256, 0, stream>>>(dst, deg, EE);
    scan_perm<<<1, 1024, 0, stream>>>(deg, row_ptr, cursor, perm, NN);
    scatter_edges<<<(EE + 255) / 256, 256, 0, stream>>>(src, dst, cursor, csr_src, EE);

    const int gy = (NN + 255) / 256;           // 79 bm super-tiles (BM=256)
    const int gy8 = ((gy + 7) / 8) * 8;        // 80 (rounded for swizzle)
    const int nagg = NN / 8;                   // 2500 blocks, 8 nodes each (2 per wave)

    // ---- layer 0: A(x f16)[N,128] -> FsH/FdH[N,256] -> O0 fp32 + A f16 ----
    gemm_mfma_f16<<<gy8 * 8, 256, 0, stream>>>(A, Wt0, bias0,
                                               FsH, FdH, nullptr, 256, 512, NN, 128, 512, 8, gy);
    gat_node_aggregate<256, 64, false, true, 0><<<nagg, 256, 0, stream>>>(
        FsH, FdH, a0, row_ptr, csr_src, perm, nullptr, 0, O0, A);

    // ---- layer 1: A -> FsH/FdH[N,256] -> A (identity residual O0 fp32) ----
    gemm_mfma_f16<<<gy8 * 8, 256, 0, stream>>>(A, Wt1, bias1,
                                               FsH, FdH, nullptr, 256, 512, NN, 256, 512, 8, gy);
    gat_node_aggregate<256, 64, true, true, 1><<<nagg, 256, 0, stream>>>(
        FsH, FdH, a1, row_ptr, csr_src, perm, O0, 256, nullptr, A);

    // ---- layer 2: A -> FsH/FdH[N,192] + Fr(=O0 fp32)[N,192] -> d_out[N,32] ----
    gemm_mfma_f16<<<gy8 * 9, 256, 0, stream>>>(A, Wt2, bias2,
                                               FsH, FdH, O0, 192, 384, NN, 256, 576, 9, gy);
    gat_node_aggregate<192, 32, true, false, 2><<<nagg, 256, 0, stream>>>(
        FsH, FdH, a2, row_ptr, csr_src, perm, O0, 192, (float*)d_out, nullptr);
}

// Round 20
// 307.292 us; speedup vs baseline: 1.4736x; 1.0532x over previous
//
#include <hip/hip_runtime.h>
#include <hip/hip_bf16.h>
#include <float.h>
#include <math.h>

// Problem constants (from reference)
#define NN 20000
#define EE 320000
#define IN_DIM 128
#define SLOPE_ 0.2f

typedef __attribute__((ext_vector_type(4))) float f32x4;
typedef _Float16 f16;
typedef __attribute__((ext_vector_type(2))) _Float16 f16x2;
typedef __attribute__((ext_vector_type(4))) _Float16 f16x4;
typedef __attribute__((ext_vector_type(8))) _Float16 f16x8;
typedef unsigned short ushort;

// ---------- weight prep element: concat + transpose, single f16 ----------
__device__ inline void prep_elem(const float* __restrict__ Wa, const float* __restrict__ ba, int na,
                                 const float* __restrict__ Wb, const float* __restrict__ bb, int nb,
                                 const float* __restrict__ Wc, const float* __restrict__ bc, int nc,
                                 int K, f16* __restrict__ Wt, float* __restrict__ bias_cat, int idx) {
    int n = idx / K;
    int k = idx - n * K;
    const float* W; const float* b; int nl; int ncols;
    if (n < na) { W = Wa; b = ba; nl = n; ncols = na; }
    else if (n < na + nb) { W = Wb; b = bb; nl = n - na; ncols = nb; }
    else { W = Wc; b = bc; nl = n - na - nb; ncols = nc; }
    Wt[(size_t)n * K + k] = (f16)W[(size_t)k * ncols + nl];
    if (k == 0) bias_cat[n] = b[nl];
}

// ---------- one launch: all 3 weight preps + x -> f16 + deg zero ----------
#define SEG0 (512 * 128)
#define SEG1 (512 * 256)
#define SEG2 (576 * 256)
#define SEG3 (NN * IN_DIM / 4)
#define SEG4 (NN)
__global__ void prep_all(const float* __restrict__ W0s, const float* __restrict__ b0s,
                         const float* __restrict__ W0d, const float* __restrict__ b0d,
                         const float* __restrict__ W1s, const float* __restrict__ b1s,
                         const float* __restrict__ W1d, const float* __restrict__ b1d,
                         const float* __restrict__ W2s, const float* __restrict__ b2s,
                         const float* __restrict__ W2d, const float* __restrict__ b2d,
                         const float* __restrict__ Wr2, const float* __restrict__ br2,
                         const float* __restrict__ x,
                         f16* __restrict__ Wt0, float* __restrict__ bias0,
                         f16* __restrict__ Wt1, float* __restrict__ bias1,
                         f16* __restrict__ Wt2, float* __restrict__ bias2,
                         f16* __restrict__ A, unsigned int* __restrict__ deg) {
    int idx = blockIdx.x * 256 + threadIdx.x;
    if (idx < SEG0) {
        prep_elem(W0s, b0s, 256, W0d, b0d, 256, nullptr, nullptr, 0, 128, Wt0, bias0, idx);
    } else if ((idx -= SEG0) < SEG1) {
        prep_elem(W1s, b1s, 256, W1d, b1d, 256, nullptr, nullptr, 0, 256, Wt1, bias1, idx);
    } else if ((idx -= SEG1) < SEG2) {
        prep_elem(W2s, b2s, 192, W2d, b2d, 192, Wr2, br2, 192, 256, Wt2, bias2, idx);
    } else if ((idx -= SEG2) < SEG3) {
        float4 v = ((const float4*)x)[idx];
        f16x4 o = {(f16)v.x, (f16)v.y, (f16)v.z, (f16)v.w};
        ((f16x4*)A)[idx] = o;
    } else if ((idx -= SEG3) < SEG4) {
        deg[idx] = 0u;
    }
}

// ---------- single-f16 MFMA GEMM v2: B-slice resident in LDS, ONE barrier total ----------
__global__ __launch_bounds__(256) void gemm_mfma_f16(
        const f16* __restrict__ A, const f16* __restrict__ Wt,
        const float* __restrict__ bias,
        f16* __restrict__ F0, f16* __restrict__ F1, float* __restrict__ F2,
        int b1, int b2, int M, int K, int S, int gx, int gy) {
    __shared__ f16 Bs[64 * 256];     // up to 32 KB, swizzled fragment order
    __shared__ f16 Cs[4][32 * 66];   // per-wave C staging, row stride 66

    const int bid = blockIdx.x;
    const int p = bid & 7;          // XCD slot
    const int q = bid >> 3;
    const int bn_i = q % gx;
    const int bm_i = (q / gx) * 8 + p;
    if (bm_i >= gy) return;
    const int bm = bm_i * 256;
    const int bn = bn_i * 64;

    const int tid = threadIdx.x;
    const int wave = tid >> 6;
    const int lane = tid & 63;
    const int m16 = lane & 15;
    const int quad = lane >> 4;

    // ---- stage whole B slice to LDS in fragment order ----
    {
        const int n = tid >> 2;      // 0..63 output col within tile
        const int q0 = tid & 3;      // quad of the 32-k chunk
        for (int j = 0; j * 32 < K; ++j) {
            int k0 = j * 32 + q0 * 8;
            f16x8 v = *(const f16x8*)(Wt + (size_t)(bn + n) * K + k0);
            int chunk = (j * 4 + (n >> 4)) * 64 + q0 * 16 + (n & 15);
            *(f16x8*)&Bs[chunk * 8] = v;
        }
    }
    __syncthreads();   // the ONLY barrier

    #pragma unroll
    for (int miter = 0; miter < 2; ++miter) {
        const int rbase = bm + wave * 64 + miter * 32;
        f32x4 acc[2][4];
        #pragma unroll
        for (int i = 0; i < 2; ++i)
            #pragma unroll
            for (int j = 0; j < 4; ++j) acc[i][j] = (f32x4){0.f, 0.f, 0.f, 0.f};

        int ar[2];
        #pragma unroll
        for (int mt = 0; mt < 2; ++mt) {
            int row = rbase + mt * 16 + m16;
            ar[mt] = row < M ? row : M - 1;
        }

        #pragma unroll 4
        for (int k0 = 0; k0 < K; k0 += 32) {
            f16x8 ah[2];
            #pragma unroll
            for (int mt = 0; mt < 2; ++mt)
                ah[mt] = *(const f16x8*)(A + (size_t)ar[mt] * K + k0 + quad * 8);
            #pragma unroll
            for (int nt = 0; nt < 4; ++nt) {
                f16x8 bs = *(const f16x8*)&Bs[(((k0 >> 5) * 4 + nt) * 64 + lane) * 8];
                #pragma unroll
                for (int mt = 0; mt < 2; ++mt)
                    acc[mt][nt] = __builtin_amdgcn_mfma_f32_16x16x32_f16(ah[mt], bs, acc[mt][nt], 0, 0, 0);
            }
        }

        // ---- epilogue for this miter ----
        if (bn < b2) {
            f16* __restrict__ Fb;
            int cs, cb;
            if (bn >= b1) { Fb = F1; cb = bn - b1; cs = b2 - b1; }
            else          { Fb = F0; cb = bn;      cs = b1; }
            f16* cw = &Cs[wave][0];
            #pragma unroll
            for (int nt = 0; nt < 4; ++nt) {
                float bv = bias[bn + nt * 16 + m16];
                #pragma unroll
                for (int mt = 0; mt < 2; ++mt)
                    #pragma unroll
                    for (int r = 0; r < 4; ++r) {
                        int row = mt * 16 + quad * 4 + r;   // 0..31 within miter
                        cw[row * 66 + nt * 16 + m16] = (f16)(acc[mt][nt][r] + bv);
                    }
            }
            int lrow = lane >> 1;
            int lcol = (lane & 1) * 32;
            int grow = rbase + lrow;
            if (grow < M) {
                #pragma unroll
                for (int j = 0; j < 4; ++j) {
                    f16x8 v = *(f16x8*)&cw[lrow * 66 + lcol + j * 8];
                    *(f16x8*)&Fb[(size_t)grow * cs + cb + lcol + j * 8] = v;
                }
            }
        } else {
            int cs = S - b2;
            #pragma unroll
            for (int nt = 0; nt < 4; ++nt) {
                int col = bn - b2 + nt * 16 + m16;
                float bv = bias[bn + nt * 16 + m16];
                #pragma unroll
                for (int mt = 0; mt < 2; ++mt)
                    #pragma unroll
                    for (int r = 0; r < 4; ++r) {
                        int row = rbase + mt * 16 + quad * 4 + r;
                        if (row < M) F2[(size_t)row * cs + col] = acc[mt][nt][r] + bv;
                    }
            }
        }
    }
}

// ---------- CSR build ----------
__global__ void hist_dst(const int* __restrict__ dst, unsigned int* __restrict__ deg, int E) {
    int e = blockIdx.x * blockDim.x + threadIdx.x;
    if (e < E) atomicAdd(&deg[dst[e]], 1u);
}

// LDS-resident coalesced exclusive scan (single block, 1024 threads).
// All global loads/stores are stride-1024 coalesced; scan work happens in LDS.
__global__ __launch_bounds__(1024) void scan_fast(const unsigned int* __restrict__ deg,
                                                  unsigned int* __restrict__ row_ptr,
                                                  unsigned int* __restrict__ cursor, int n) {
    __shared__ unsigned int vals[NN];     // 80 KB
    __shared__ unsigned int sums[1024];
    const int t = threadIdx.x;
    // coalesced load
    for (int i = t; i < n; i += 1024) vals[i] = deg[i];
    __syncthreads();
    // per-chunk serial exclusive scan in LDS
    const int chunk = (n + 1023) / 1024;
    const int start = t * chunk;
    const int end = min(start + chunk, n);
    unsigned int s = 0;
    for (int i = start; i < end; ++i) { unsigned int d = vals[i]; vals[i] = s; s += d; }
    sums[t] = s;
    __syncthreads();
    // Hillis-Steele inclusive scan over 1024 partials
    for (int off = 1; off < 1024; off <<= 1) {
        unsigned int v = (t >= off) ? sums[t - off] : 0u;
        __syncthreads();
        sums[t] += v;
        __syncthreads();
    }
    const unsigned int prefix = (t == 0) ? 0u : sums[t - 1];
    for (int i = start; i < end; ++i) vals[i] += prefix;
    __syncthreads();
    // coalesced store
    for (int i = t; i < n; i += 1024) {
        unsigned int v = vals[i];
        row_ptr[i] = v;
        cursor[i] = v;
    }
    if (t == 1023) row_ptr[n] = sums[1023];
}

__global__ void scatter_edges(const int* __restrict__ src, const int* __restrict__ dst,
                              unsigned int* __restrict__ cursor,
                              int* __restrict__ csr_src, int E) {
    int e = blockIdx.x * blockDim.x + threadIdx.x;
    if (e < E) {
        unsigned int pos = atomicAdd(&cursor[dst[e]], 1u);
        csr_src[pos] = src[e];
    }
}

// ---------- fused GATv2 aggregate: 2 nodes per wave, 8 f16 dims per lane ----------
// Identity node order. In-place index refill. Packed-f16 logit dot + plain exp-sum.
// OUT_MODE: 0 = fp32 out + f16 A; 1 = f16 A only; 2 = head-mean -> out[N,32].
template <int HD, int D, bool HAS_RES, bool DO_ELU, int OUT_MODE>
__global__ __launch_bounds__(256) void gat_node_aggregate(
        const f16* __restrict__ fsb, const f16* __restrict__ fdb,
        const float* __restrict__ attn,
        const unsigned int* __restrict__ row_ptr,
        const int* __restrict__ csr_src,
        const float* __restrict__ resid, int RS,
        float* __restrict__ outF, f16* __restrict__ outA) {
    constexpr int LANES = HD / 8;   // active lanes per node (32 or 24)
    constexpr int GSZ = D / 8;      // lanes per head group (8 or 4)
    __shared__ float red[(OUT_MODE == 2) ? 8 : 1][(OUT_MODE == 2) ? HD : 1];

    const int wave = threadIdx.x >> 6;
    const int lane = threadIdx.x & 63;
    const int half = lane >> 5;            // 0 = node A, 1 = node B
    const int ln = lane & 31;              // lane within node
    const int t = blockIdx.x * 8 + wave * 2 + half;
    const bool active = (ln < LANES);
    const unsigned off = active ? 8u * ln : 0u;   // inactive lanes alias dims 0-7

    f16x2 fdp[4], a6p[4], a4p[4];
    if (active) {
        f16x8 dv = *(const f16x8*)&fdb[(unsigned)t * HD + off];
        float4 aA = *(const float4*)&attn[off];
        float4 aB = *(const float4*)&attn[off + 4];
        float av[8] = {aA.x, aA.y, aA.z, aA.w, aB.x, aB.y, aB.z, aB.w};
        #pragma unroll
        for (int i = 0; i < 4; ++i) {
            fdp[i] = (f16x2){dv[2 * i], dv[2 * i + 1]};
            a6p[i] = (f16x2){(f16)(0.6f * av[2 * i]), (f16)(0.6f * av[2 * i + 1])};
            a4p[i] = (f16x2){(f16)(0.4f * av[2 * i]), (f16)(0.4f * av[2 * i + 1])};
        }
    } else {
        #pragma unroll
        for (int i = 0; i < 4; ++i) {
            fdp[i] = (f16x2){0, 0};
            a6p[i] = (f16x2){0, 0};
            a4p[i] = (f16x2){0, 0};
        }
    }

    const int jj0 = (int)row_ptr[t];
    const int jj1 = (int)row_ptr[t + 1];
    const int deg = jj1 - jj0;
    const int last = jj1 - 1;
    const int degO = __shfl_xor(deg, 32, 64);
    const int mdeg = max(deg, degO);       // wave-uniform loop bound

    float acc[8];
    #pragma unroll
    for (int d = 0; d < 8; ++d) acc[d] = 0.f;
    float lh = 0.f;

    // prologue: features for edges 0..7, indices for refill edges 8..15 (all clamped)
    f16x8 buf[8];
    int cidx[8];
    #pragma unroll
    for (int u = 0; u < 8; ++u) {
        int e0 = min(jj0 + u, last);
        buf[u] = *(const f16x8*)&fsb[(unsigned)csr_src[e0] * HD + off];
        cidx[u] = csr_src[min(jj0 + 8 + u, last)];
    }

    for (int b = 0; b < mdeg; b += 8) {
        #pragma unroll
        for (int u = 0; u < 8; ++u) {
            const f16x8 cur = buf[u];
            buf[u] = *(const f16x8*)&fsb[(unsigned)cidx[u] * HD + off];  // edge b+8+u
            cidx[u] = csr_src[min(jj0 + b + 16 + u, last)];             // edge b+16+u
            float p = 0.f;
            #pragma unroll
            for (int i = 0; i < 4; ++i) {
                f16x2 cp = (f16x2){cur[2 * i], cur[2 * i + 1]};
                f16x2 xp = cp + fdp[i];                       // v_pk_add_f16
                unsigned xu = __builtin_bit_cast(unsigned, xp) & 0x7FFF7FFFu;
                f16x2 xa = __builtin_bit_cast(f16x2, xu);     // packed |x|
                p = __builtin_amdgcn_fdot2(xp, a6p[i], p, false);
                p = __builtin_amdgcn_fdot2(xa, a4p[i], p, false);
            }
            #pragma unroll
            for (int o = 1; o < GSZ; o <<= 1)
                p += __shfl_xor(p, o, 64);
            float w = (b + u < deg) ? __expf(p) : 0.f;
            lh += w;
            #pragma unroll
            for (int d = 0; d < 8; ++d) acc[d] += w * (float)cur[d];   // fma_mix
        }
    }

    float inv = (lh > 0.f) ? 1.f / lh : 0.f;
    float vout[8];
    #pragma unroll
    for (int d = 0; d < 8; ++d) vout[d] = acc[d] * inv;
    if (HAS_RES && active) {
        float4 rA = *(const float4*)&resid[(unsigned)t * RS + off];
        float4 rB = *(const float4*)&resid[(unsigned)t * RS + off + 4];
        vout[0] += rA.x; vout[1] += rA.y; vout[2] += rA.z; vout[3] += rA.w;
        vout[4] += rB.x; vout[5] += rB.y; vout[6] += rB.z; vout[7] += rB.w;
    }
    if (DO_ELU) {
        #pragma unroll
        for (int d = 0; d < 8; ++d) vout[d] = vout[d] > 0.f ? vout[d] : expm1f(vout[d]);
    }

    if (OUT_MODE == 2) {
        const int nib = wave * 2 + half;
        if (active) {
            *(float4*)&red[nib][off] = make_float4(vout[0], vout[1], vout[2], vout[3]);
            *(float4*)&red[nib][off + 4] = make_float4(vout[4], vout[5], vout[6], vout[7]);
        }
        __syncthreads();
        // 8 nodes x 32 cols = 256 threads
        int node = threadIdx.x >> 5;
        int col = threadIdx.x & 31;
        float ssum = 0.f;
        #pragma unroll
        for (int h = 0; h < 6; ++h) ssum += red[node][h * 32 + col];
        outF[(unsigned)(blockIdx.x * 8 + node) * 32 + col] = ssum * (1.f / 6.f);
    } else if (active) {
        f16x8 av;
        #pragma unroll
        for (int d = 0; d < 8; ++d) av[d] = (f16)vout[d];
        *(f16x8*)&outA[(unsigned)t * HD + off] = av;
        if (OUT_MODE == 0) {
            *(float4*)&outF[(unsigned)t * HD + off] = make_float4(vout[0], vout[1], vout[2], vout[3]);
            *(float4*)&outF[(unsigned)t * HD + off + 4] = make_float4(vout[4], vout[5], vout[6], vout[7]);
        }
    }
}

extern "C" void kernel_launch(void* const* d_in, const int* in_sizes, int n_in,
                              void* d_out, int out_size, void* d_ws, size_t ws_size,
                              hipStream_t stream) {
    const float* x   = (const float*)d_in[0];
    const int*   src = (const int*)d_in[1];
    const int*   dst = (const int*)d_in[2];
    const float* W0s = (const float*)d_in[3];
    const float* b0s = (const float*)d_in[4];
    const float* W0d = (const float*)d_in[5];
    const float* b0d = (const float*)d_in[6];
    const float* a0  = (const float*)d_in[7];
    const float* W1s = (const float*)d_in[8];
    const float* b1s = (const float*)d_in[9];
    const float* W1d = (const float*)d_in[10];
    const float* b1d = (const float*)d_in[11];
    const float* a1  = (const float*)d_in[12];
    const float* W2s = (const float*)d_in[13];
    const float* b2s = (const float*)d_in[14];
    const float* W2d = (const float*)d_in[15];
    const float* b2d = (const float*)d_in[16];
    const float* a2  = (const float*)d_in[17];
    const float* Wr2 = (const float*)d_in[18];
    const float* br2 = (const float*)d_in[19];

    // ---- workspace layout ----
    f16* FsH = (f16*)d_ws;                           // N*256 f16 (fs, dense gather target)
    f16* FdH = FsH + (size_t)NN * 256;               // N*256 f16 (fd)
    f16* A   = FdH + (size_t)NN * 256;               // N*256 f16 (GEMM A input)
    float* O0 = (float*)(A + (size_t)NN * 256);      // N*256 fp32 (L1 residual; later L2 Fr N*192)
    f16* Wt0 = (f16*)(O0 + (size_t)NN * 256);        // 512*128
    f16* Wt1 = Wt0 + 512 * 128;                      // 512*256
    f16* Wt2 = Wt1 + 512 * 256;                      // 576*256
    float* bias0 = (float*)(Wt2 + 576 * 256);        // 512
    float* bias1 = bias0 + 512;                      // 512
    float* bias2 = bias1 + 512;                      // 576
    unsigned int* row_ptr = (unsigned int*)(bias2 + 576);  // N+1
    unsigned int* cursor  = row_ptr + (NN + 1);
    unsigned int* deg     = cursor + NN;
    int* csr_src          = (int*)(deg + NN);        // E

    // ---- prep (weights + x->f16 + deg zero), then CSR chain ----
    {
        int total = SEG0 + SEG1 + SEG2 + SEG3 + SEG4;
        prep_all<<<(total + 255) / 256, 256, 0, stream>>>(
            W0s, b0s, W0d, b0d, W1s, b1s, W1d, b1d, W2s, b2s, W2d, b2d, Wr2, br2, x,
            Wt0, bias0, Wt1, bias1, Wt2, bias2, A, deg);
    }
    hist_dst<<<(EE + 255) / 256, 256, 0, stream>>>(dst, deg, EE);
    scan_fast<<<1, 1024, 0, stream>>>(deg, row_ptr, cursor, NN);
    scatter_edges<<<(EE + 255) / 256, 256, 0, stream>>>(src, dst, cursor, csr_src, EE);

    const int gy = (NN + 255) / 256;           // 79 bm super-tiles (BM=256)
    const int gy8 = ((gy + 7) / 8) * 8;        // 80 (rounded for swizzle)
    const int nagg = NN / 8;                   // 2500 blocks, 8 nodes each (2 per wave)

    // ---- layer 0: A(x f16)[N,128] -> FsH/FdH[N,256] -> O0 fp32 + A f16 ----
    gemm_mfma_f16<<<gy8 * 8, 256, 0, stream>>>(A, Wt0, bias0,
                                               FsH, FdH, nullptr, 256, 512, NN, 128, 512, 8, gy);
    gat_node_aggregate<256, 64, false, true, 0><<<nagg, 256, 0, stream>>>(
        FsH, FdH, a0, row_ptr, csr_src, nullptr, 0, O0, A);

    // ---- layer 1: A -> FsH/FdH[N,256] -> A (identity residual O0 fp32) ----
    gemm_mfma_f16<<<gy8 * 8, 256, 0, stream>>>(A, Wt1, bias1,
                                               FsH, FdH, nullptr, 256, 512, NN, 256, 512, 8, gy);
    gat_node_aggregate<256, 64, true, true, 1><<<nagg, 256, 0, stream>>>(
        FsH, FdH, a1, row_ptr, csr_src, O0, 256, nullptr, A);

    // ---- layer 2: A -> FsH/FdH[N,192] + Fr(=O0 fp32)[N,192] -> d_out[N,32] ----
    gemm_mfma_f16<<<gy8 * 9, 256, 0, stream>>>(A, Wt2, bias2,
                                               FsH, FdH, O0, 192, 384, NN, 256, 576, 9, gy);
    gat_node_aggregate<192, 32, true, false, 2><<<nagg, 256, 0, stream>>>(
        FsH, FdH, a2, row_ptr, csr_src, O0, 192, (float*)d_out, nullptr);
}